// Round 15
// baseline (693.504 us; speedup 1.0000x reference)
//
#include <hip/hip_runtime.h>
#include <math.h>

#define CDIM 2048
#define TDIM 2048
#define BDIM 4
#define HDIM 16
#define DDIM 128
#define M1   (BDIM * TDIM)   // 8192
#define N1   (3 * CDIM)      // 6144
#define KK   CDIM            // 2048
#define NT   32              // K tiles of 64

typedef unsigned short u16;
typedef __bf16 bf16x8 __attribute__((ext_vector_type(8)));
typedef float f32x4 __attribute__((ext_vector_type(4)));

// ---------- helpers ----------
__device__ __forceinline__ u16 f2b(float f) {
  union { float f; unsigned u; } x; x.f = f;
  unsigned r = x.u + 0x7fffu + ((x.u >> 16) & 1u);
  return (u16)(r >> 16);
}

__device__ __forceinline__ void gload_lds16(const void* g, void* l) {
  __builtin_amdgcn_global_load_lds(
      (__attribute__((address_space(1))) void*)g,
      (__attribute__((address_space(3))) void*)l, 16, 0, 0);
}

// ---------- small prep kernels ----------
__global__ void convert_x(const float* __restrict__ x, u16* __restrict__ xb, int n4) {
  int i = blockIdx.x * blockDim.x + threadIdx.x;
  if (i < n4) {
    float4 v = ((const float4*)x)[i];
    unsigned long long o = (unsigned long long)f2b(v.x)
                         | ((unsigned long long)f2b(v.y) << 16)
                         | ((unsigned long long)f2b(v.z) << 32)
                         | ((unsigned long long)f2b(v.w) << 48);
    ((unsigned long long*)xb)[i] = o;
  }
}

// w [K][N] fp32 -> wt [N][K] bf16
__global__ void transpose_w(const float* __restrict__ w, u16* __restrict__ wt, int K, int N) {
  __shared__ float tile[32][33];
  const int n0 = blockIdx.x * 32, k0 = blockIdx.y * 32;
  const int tx = threadIdx.x & 31, ty = threadIdx.x >> 5;
  for (int r = ty; r < 32; r += 8)
    tile[r][tx] = w[(k0 + r) * N + n0 + tx];
  __syncthreads();
  for (int r = ty; r < 32; r += 8)
    wt[(n0 + r) * K + k0 + tx] = f2b(tile[tx][r]);
}

// f32 rope table (reference computes freqs/cos in f32; f32 here matches it)
__global__ void rope_tab(float* __restrict__ cosT, float* __restrict__ sinT) {
  int i = blockIdx.x * blockDim.x + threadIdx.x;   // 0 .. 2048*64-1
  int t = i >> 6, d = i & 63;
  // inv = 10000^(-d/64) = exp2(-d * log2(10000)/64)
  float inv = exp2f(-(float)d * (13.287712379549449f / 64.0f));
  float a = (float)t * inv;
  cosT[i] = cosf(a);
  sinT[i] = sinf(a);
}

// =====================================================================
// 256x256-tile, BK=64, 8-wave (2Mx4N) GEMM — R5 schedule (best measured:
// ~227 us gemm_qkv, MfmaUtil 39% = the ~900 TF 2-barrier-structure
// ceiling). Quadrant-pipelined K-tile; 2 barriers + 2 counted vmcnt/tile.
// =====================================================================

#define VMW4 asm volatile("s_waitcnt vmcnt(4)" ::: "memory");
#define VMW2 asm volatile("s_waitcnt vmcnt(2)" ::: "memory");
#define VMW0 asm volatile("s_waitcnt vmcnt(0)" ::: "memory");
#define NOWAIT

#define GEMM256_TILE(bufA_, bufB_, nA_, nB_, kno_, STG, WMID, WEND)            \
  {                                                                            \
    __builtin_amdgcn_s_barrier();  /* publishes A-lo,B-lo,B-hi(t); WAR */      \
    bf16x8 aX[4][2], aY[4][2], bX[2][2], bY[2][2];                             \
    /* q0 frags: A-lo, B-lo */                                                 \
    _Pragma("unroll")                                                          \
    for (int i = 0; i < 4; ++i)                                                \
      _Pragma("unroll")                                                        \
      for (int kh = 0; kh < 2; ++kh)                                           \
        aX[i][kh] = *(const bf16x8*)&(bufA_)[aoff + i * 1024 +                 \
                                             (((kh * 4 + quad) ^ rsw) * 8)];   \
    _Pragma("unroll")                                                          \
    for (int j = 0; j < 2; ++j)                                                \
      _Pragma("unroll")                                                        \
      for (int kh = 0; kh < 2; ++kh)                                           \
        bX[j][kh] = *(const bf16x8*)&(bufB_)[boff + j * 1024 +                 \
                                             (((kh * 4 + quad) ^ rsw) * 8)];   \
    /* q0: m-lo x n-lo */                                                      \
    __builtin_amdgcn_s_setprio(1);                                             \
    _Pragma("unroll")                                                          \
    for (int i = 0; i < 4; ++i)                                                \
      _Pragma("unroll")                                                        \
      for (int j = 0; j < 2; ++j)                                              \
        _Pragma("unroll")                                                      \
        for (int kh = 0; kh < 2; ++kh)                                         \
          acc[i][j] = __builtin_amdgcn_mfma_f32_16x16x32_bf16(                 \
              aX[i][kh], bX[j][kh], acc[i][j], 0, 0, 0);                       \
    __builtin_amdgcn_s_setprio(0);                                             \
    /* pre-read q1 frags: B-hi (headroom: stage + vmcnt + barrier) */          \
    _Pragma("unroll")                                                          \
    for (int j = 0; j < 2; ++j)                                                \
      _Pragma("unroll")                                                        \
      for (int kh = 0; kh < 2; ++kh)                                           \
        bY[j][kh] = *(const bf16x8*)&(bufB_)[8192 + boff + j * 1024 +          \
                                             (((kh * 4 + quad) ^ rsw) * 8)];   \
    if (STG) {                                                                 \
      _Pragma("unroll")                                                        \
      for (int q = 0; q < 2; ++q)                                              \
        gload_lds16(AgBase + (q * 128) * KK + (kno_), &(nA_)[q * 4096 + ldsw]);\
      _Pragma("unroll")                                                        \
      for (int q = 0; q < 2; ++q)                                              \
        gload_lds16(BgBase + (q * 128) * KK + (kno_),                          \
                    &(nB_)[q * 4096 + ldsw]);                                  \
    }                                                                          \
    WMID                                                                       \
    __builtin_amdgcn_s_barrier();  /* publishes A-hi(t) */                     \
    /* q1: m-lo x n-hi (aX, bY already in regs) */                             \
    __builtin_amdgcn_s_setprio(1);                                             \
    _Pragma("unroll")                                                          \
    for (int i = 0; i < 4; ++i)                                                \
      _Pragma("unroll")                                                        \
      for (int j = 0; j < 2; ++j)                                              \
        _Pragma("unroll")                                                      \
        for (int kh = 0; kh < 2; ++kh)                                         \
          acc[i][2 + j] = __builtin_amdgcn_mfma_f32_16x16x32_bf16(             \
              aX[i][kh], bY[j][kh], acc[i][2 + j], 0, 0, 0);                   \
    __builtin_amdgcn_s_setprio(0);                                             \
    /* pre-read q2 frags: A-hi (headroom: one MFMA cluster + stage) */         \
    _Pragma("unroll")                                                          \
    for (int i = 0; i < 4; ++i)                                                \
      _Pragma("unroll")                                                        \
      for (int kh = 0; kh < 2; ++kh)                                           \
        aY[i][kh] = *(const bf16x8*)&(bufA_)[8192 + aoff + i * 1024 +          \
                                             (((kh * 4 + quad) ^ rsw) * 8)];   \
    if (STG) {                                                                 \
      _Pragma("unroll")                                                        \
      for (int q = 0; q < 2; ++q)                                              \
        gload_lds16(BgBase + (q * 128 + 32) * KK + (kno_),                     \
                    &(nB_)[8192 + q * 4096 + ldsw]);                           \
    }                                                                          \
    /* q2: m-hi x n-hi */                                                      \
    __builtin_amdgcn_s_setprio(1);                                             \
    _Pragma("unroll")                                                          \
    for (int i = 0; i < 4; ++i)                                                \
      _Pragma("unroll")                                                        \
      for (int j = 0; j < 2; ++j)                                              \
        _Pragma("unroll")                                                      \
        for (int kh = 0; kh < 2; ++kh)                                         \
          acc[4 + i][2 + j] = __builtin_amdgcn_mfma_f32_16x16x32_bf16(         \
              aY[i][kh], bY[j][kh], acc[4 + i][2 + j], 0, 0, 0);               \
    __builtin_amdgcn_s_setprio(0);                                             \
    if (STG) {                                                                 \
      _Pragma("unroll")                                                        \
      for (int q = 0; q < 2; ++q)                                              \
        gload_lds16(AgBase + (q * 128 + 64) * KK + (kno_),                     \
                    &(nA_)[8192 + q * 4096 + ldsw]);                           \
    }                                                                          \
    /* q3: m-hi x n-lo (aY, bX already in regs — no re-read) */                \
    __builtin_amdgcn_s_setprio(1);                                             \
    _Pragma("unroll")                                                          \
    for (int i = 0; i < 4; ++i)                                                \
      _Pragma("unroll")                                                        \
      for (int j = 0; j < 2; ++j)                                              \
        _Pragma("unroll")                                                      \
        for (int kh = 0; kh < 2; ++kh)                                         \
          acc[4 + i][j] = __builtin_amdgcn_mfma_f32_16x16x32_bf16(             \
              aY[i][kh], bX[j][kh], acc[4 + i][j], 0, 0, 0);                   \
    __builtin_amdgcn_s_setprio(0);                                             \
    WEND                                                                       \
  }

#define GEMM256_MAINLOOP(APTR, BPTR)                                           \
  const int rA = lane >> 3, cA = lane & 7;                                     \
  const int w8r = wave * 8 + rA;                                               \
  const int swz8 = (cA ^ rA) * 8;                                              \
  const u16* AgBase = (APTR) + (m0 + w8r) * KK + swz8;                         \
  const int nb = ((w8r >> 5) * 64) + (w8r & 31);                               \
  const u16* BgBase = (BPTR) + (n0 + nb) * KK + swz8;                          \
  const int ldsw = wave * 512;                                                 \
  const int rsw = c16 & 7;                                                     \
  const int aoff = (((wave >> 2) * 64) + c16) * 64;                            \
  const int boff = (((wave & 3) * 32) + c16) * 64;                             \
  f32x4 acc[8][4];                                                             \
  {                                                                            \
    f32x4 z = {0.f, 0.f, 0.f, 0.f};                                            \
    _Pragma("unroll")                                                          \
    for (int i = 0; i < 8; ++i)                                                \
      _Pragma("unroll")                                                        \
      for (int j = 0; j < 4; ++j) acc[i][j] = z;                               \
  }                                                                            \
  /* prologue: stage tile 0 (A-lo, B-lo, B-hi, A-hi); keep A-hi in flight */   \
  _Pragma("unroll")                                                            \
  for (int q = 0; q < 2; ++q)                                                  \
    gload_lds16(AgBase + (q * 128) * KK, &lds[q * 4096 + ldsw]);               \
  _Pragma("unroll")                                                            \
  for (int q = 0; q < 2; ++q)                                                  \
    gload_lds16(BgBase + (q * 128) * KK, &lds[32768 + q * 4096 + ldsw]);       \
  _Pragma("unroll")                                                            \
  for (int q = 0; q < 2; ++q)                                                  \
    gload_lds16(BgBase + (q * 128 + 32) * KK,                                  \
                &lds[32768 + 8192 + q * 4096 + ldsw]);                         \
  _Pragma("unroll")                                                            \
  for (int q = 0; q < 2; ++q)                                                  \
    gload_lds16(AgBase + (q * 128 + 64) * KK, &lds[8192 + q * 4096 + ldsw]);   \
  VMW2                                                                         \
  for (int kt = 0; kt < NT - 1; ++kt) {                                        \
    const int cur = kt & 1;                                                    \
    const u16* bA = &lds[cur * 16384];                                         \
    const u16* bB = &lds[32768 + cur * 16384];                                 \
    u16* nA = &lds[(cur ^ 1) * 16384];                                         \
    u16* nB = &lds[32768 + (cur ^ 1) * 16384];                                 \
    const int kno = (kt + 1) * 64;                                             \
    GEMM256_TILE(bA, bB, nA, nB, kno, 1, VMW4, VMW2)                           \
  }                                                                            \
  /* tail tile NT-1 (odd -> buf1): no staging; mid wait drains A-hi */         \
  GEMM256_TILE((&lds[16384]), (&lds[32768 + 16384]), (&lds[0]),                \
               (&lds[32768]), 0, 0, VMW0, NOWAIT)

// ---------- GEMM1: qkv = x @ w_qkv, epilogue: rope + scatter + fused V^T ----
__global__ __launch_bounds__(512, 1) void gemm_qkv(
    const u16* __restrict__ A,    // xb [8192][2048]
    const u16* __restrict__ Bt,   // wqkvT [6144][2048]
    const float* __restrict__ cosT, const float* __restrict__ sinT,
    u16* __restrict__ qb, u16* __restrict__ kb,
    float* __restrict__ kout, float* __restrict__ vout,
    u16* __restrict__ vtout)
{
  extern __shared__ __align__(16) u16 lds[];   // 131072 B
  const int tid = threadIdx.x, wave = tid >> 6, lane = tid & 63;
  const int quad = lane >> 4, c16 = lane & 15;
  // bijective XCD swizzle: nwg = 24*32 = 768, 768 % 8 == 0, cpx = 96
  const int bid = blockIdx.y * 24 + blockIdx.x;
  const int swz = (bid & 7) * 96 + (bid >> 3);
  const int m0 = (swz / 24) * 256, n0 = (swz % 24) * 256;

  GEMM256_MAINLOOP(A, Bt)

  // ---- epilogue: rope + scatter, 4 passes of 64 rows through LDS ----
  // NOTE: pass loop MUST be fully unrolled — acc[] indexed by pass-derived
  // values; runtime indexing would demote acc to scratch (rule #20, R2 bug).
  float* cbuf = (float*)lds;                  // [64][261] fp32 = 66.8 KB
  const int mat = n0 >> 11;                   // 0=q, 1=k, 2=v (block-uniform)
  const int hbase = (n0 & 2047) >> 7;
  // 1/sqrt(128) * log2(e) folded into q (attn uses exp2)
  const float qscale = 0.1275178689414753f;
#pragma unroll
  for (int pass = 0; pass < 4; ++pass) {
    __syncthreads();
    if ((wave >> 2) == (pass >> 1)) {
#pragma unroll
      for (int i = 0; i < 4; ++i) {
        const int mf = (pass & 1) * 4 + i;
#pragma unroll
        for (int j = 0; j < 4; ++j)
#pragma unroll
          for (int r = 0; r < 4; ++r)
            cbuf[(i * 16 + quad * 4 + r) * 261 + (wave & 3) * 64 + j * 16 + c16] = acc[mf][j][r];
      }
    }
    __syncthreads();
#pragma unroll
    for (int it = 0; it < 16; ++it) {
      int p = it * 512 + tid;          // 0..8191
      int lr = p >> 7;                 // local row 0..63
      int hc = (p >> 6) & 1;           // head-chunk within 256-wide tile
      int d = p & 63;
      float x1 = cbuf[lr * 261 + hc * 128 + d];
      float x2 = cbuf[lr * 261 + hc * 128 + 64 + d];
      int mg = m0 + pass * 64 + lr;
      int b = mg >> 11, t = mg & 2047;
      int h = hbase + hc;
      int idx = ((b * HDIM + h) * TDIM + t) * DDIM + d;
      if (mat == 2) {
        vout[idx] = x1; vout[idx + 64] = x2;
      } else {
        float cs = cosT[t * 64 + d], sn = sinT[t * 64 + d];
        float o1 = x1 * cs - x2 * sn;
        float o2 = x1 * sn + x2 * cs;
        if (mat == 0) {
          qb[idx] = f2b(o1 * qscale); qb[idx + 64] = f2b(o2 * qscale);
        } else {
          kout[idx] = o1; kout[idx + 64] = o2;
          kb[idx] = f2b(o1); kb[idx + 64] = f2b(o2);
        }
      }
    }
    // fused V^T: vt[bh][d][t] bf16, coalesced along t (replaces transpose_v)
    if (mat == 2) {
#pragma unroll
      for (int it = 0; it < 16; ++it) {
        int p = it * 512 + tid;        // 0..8191
        int tl = p & 63;               // t_local (lanes 0-63 share column)
        int c2 = p >> 6;               // 0..127  (d within head)
        float xA = cbuf[tl * 261 + c2];
        float xB = cbuf[tl * 261 + 128 + c2];
        int mg = m0 + pass * 64 + tl;
        int b = mg >> 11, t = mg & 2047;
        vtout[((b * HDIM + hbase) * DDIM + c2) * TDIM + t] = f2b(xA);
        vtout[((b * HDIM + hbase + 1) * DDIM + c2) * TDIM + t] = f2b(xB);
      }
    }
  }
}

// ---------- GEMM2: out = att @ w_proj ----------
__global__ __launch_bounds__(512, 1) void gemm_proj(
    const u16* __restrict__ A,    // att [8192][2048]
    const u16* __restrict__ Bt,   // wprojT [2048][2048]
    float* __restrict__ out)
{
  extern __shared__ __align__(16) u16 lds[];   // 131072 B
  const int tid = threadIdx.x, wave = tid >> 6, lane = tid & 63;
  const int quad = lane >> 4, c16 = lane & 15;
  // bijective XCD swizzle: nwg = 8*32 = 256, cpx = 32
  const int bid = blockIdx.y * 8 + blockIdx.x;
  const int swz = (bid & 7) * 32 + (bid >> 3);
  const int m0 = (swz >> 3) * 256, n0 = (swz & 7) * 256;

  GEMM256_MAINLOOP(A, Bt)

  const int wm = (wave >> 2) * 128, wn = (wave & 3) * 64;
#pragma unroll
  for (int mf = 0; mf < 8; ++mf)
#pragma unroll
    for (int nf = 0; nf < 4; ++nf)
#pragma unroll
      for (int r = 0; r < 4; ++r)
        out[(m0 + wm + mf * 16 + quad * 4 + r) * CDIM + n0 + wn + nf * 16 + c16] =
            acc[mf][nf][r];
}

// ---------- flash attention: 8-wave blocks, paired tiles, dbuf K/V ----------
// R14 structure + XCD-locality remap: grid (8,64), hardware block id =
// by*8+bx so XCD = bx. Assign bh = (by & ~7) | bx and pair-slot p = by & 7:
// all 8 blocks sharing one bh's K/V panel then have the SAME bx -> same
// XCD -> the 1 MB panel is fetched into one L2 once (was 8 XCDs x 1 fetch:
// FETCH measured 233 MB vs 67 MB unique). Chunk reads become L2 hits
// (~200cy) which the 1-deep prefetch fully hides. Bijective remap; compute
// identical (static-max softmax, counted-vmcnt dbuf pipeline).
__global__ __launch_bounds__(512, 4) void attn(
    const u16* __restrict__ qb, const u16* __restrict__ kb,
    const u16* __restrict__ vt, u16* __restrict__ att)
{
  extern __shared__ __align__(16) u16 sh[];   // 81920 B dynamic
  u16* const psm = sh + 32768;        // per-wave 1024 u16 P buffer

  const int tid = threadIdx.x, wave = tid >> 6, lane = tid & 63;
  const int quad = lane >> 4, c16 = lane & 15;
  const int p_slot = blockIdx.y & 7;                 // pair slot 0..7
  const int bh = (blockIdx.y & ~7) | blockIdx.x;     // same-XCD bh grouping

  // staging lane constants
  const int rlK = wave * 4 + (lane >> 4), chK = lane & 15;   // K/Q: 4-row strips
  const int rlV = wave * 8 + (lane >> 3), chV = lane & 7;    // V: 8-row strips

  for (int hv = 0; hv < 2; ++hv) {
    const int qt = hv ? (7 - p_slot) : (p_slot + 8);   // heavy tile first; 34 chunks
    const int q0 = qt * 128;

    // ---- stage Q (128x128) into sh[0,16384) u16 (32 KB), extract frags ----
    {
      const u16* qg = qb + (bh * TDIM + q0) * DDIM;
#pragma unroll
      for (int r = 0; r < 4; ++r) {
        int row = r * 32 + rlK;
        gload_lds16(qg + row * DDIM + (chK ^ (row & 15)) * 8,
                    &sh[(r * 32 + wave * 4) * 128]);
      }
    }
    __syncthreads();
    bf16x8 qf[4];
#pragma unroll
    for (int kp = 0; kp < 4; ++kp)
      qf[kp] = *(const bf16x8*)&sh[(wave * 16 + c16) * 128 +
                                   (((kp * 4 + quad) ^ c16) * 8)];
    __syncthreads();   // all waves done reading Q area -> reusable for K/V

    f32x4 o[8];
    f32x4 zero = {0.f, 0.f, 0.f, 0.f};
#pragma unroll
    for (int jd = 0; jd < 8; ++jd) o[jd] = zero;
    float lrow[4];
#pragma unroll
    for (int r = 0; r < 4; ++r) lrow[r] = 0.f;

    const int nchunk = 2 * qt + 2;

#define STAGE_KV(kcs, bufbase)                                                 \
    {                                                                          \
      const int kcs0 = (kcs) * 64;                                             \
      const u16* kg = kb + (bh * TDIM + kcs0) * DDIM;                          \
      _Pragma("unroll")                                                        \
      for (int r = 0; r < 2; ++r) {                                            \
        int row = r * 32 + rlK;                                                \
        gload_lds16(kg + row * DDIM + (chK ^ (row & 15)) * 8,                  \
                    &sh[(bufbase) + (r * 32 + wave * 4) * 128]);               \
      }                                                                        \
      const u16* vg = vt + bh * (DDIM * TDIM) + kcs0;                          \
      _Pragma("unroll")                                                        \
      for (int r = 0; r < 2; ++r) {                                            \
        int row = r * 64 + rlV;                                                \
        gload_lds16(vg + row * TDIM + (chV ^ (row & 7)) * 8,                   \
                    &sh[(bufbase) + 8192 + (r * 64 + wave * 8) * 64]);         \
      }                                                                        \
    }

    // prologue: stage chunk 0 into buf0 (4 loads/thread outstanding)
    STAGE_KV(0, 0)

    for (int kc = 0; kc < nchunk; ++kc) {
      const int kc0 = kc * 64;
      const int cur = kc & 1;
      const u16* ksm = sh + cur * 16384;
      const u16* vsm = ksm + 8192;

      // issue next chunk's staging into buf^1 (WAR-safe: its readers
      // finished before the end-barrier of iteration kc-1)
      if (kc + 1 < nchunk) {
        STAGE_KV(kc + 1, (cur ^ 1) * 16384)
        asm volatile("s_waitcnt vmcnt(4)" ::: "memory");  // completes kc's 4
      } else {
        asm volatile("s_waitcnt vmcnt(0)" ::: "memory");  // drain last
      }
      asm volatile("s_barrier" ::: "memory");             // publish chunk kc

      // S = Q K^T (log2-domain: scale*log2e pre-folded into Q)
      f32x4 st[4];
#pragma unroll
      for (int j = 0; j < 4; ++j) st[j] = zero;
#pragma unroll
      for (int kp = 0; kp < 4; ++kp) {
#pragma unroll
        for (int j = 0; j < 4; ++j) {
          bf16x8 bk = *(const bf16x8*)&ksm[(j * 16 + c16) * 128 +
                                           (((kp * 4 + quad) ^ c16) * 8)];
          st[j] = __builtin_amdgcn_mfma_f32_16x16x32_bf16(qf[kp], bk, st[j], 0, 0, 0);
        }
      }

      // static-max softmax: P = exp2(S - 8); no max tracking, no rescale,
      // no cross-lane reduce here (lrow partial per lane; reduced at end).
      u16* const pw = psm + wave * 1024;
      const bool dg = (kc0 + 63 > q0 + wave * 16);
      const int qrow_base = q0 + wave * 16 + quad * 4;
#pragma unroll
      for (int r = 0; r < 4; ++r) {
        const int row16 = quad * 4 + r;
        float sum = 0.f;
#pragma unroll
        for (int j = 0; j < 4; ++j) {
          float sv = st[j][r];
          if (dg && (kc0 + j * 16 + c16 > qrow_base + r)) sv = -INFINITY;
          float p = exp2f(sv - 8.0f);
          sum += p;
          int chunk = (j * 2 + (c16 >> 3)) ^ (row16 & 7);
          pw[row16 * 64 + chunk * 8 + (c16 & 7)] = f2b(p);
        }
        lrow[r] += sum;
      }

      asm volatile("s_waitcnt lgkmcnt(0)" ::: "memory");

      // O += P V   (P layout: row16*64 + chunk*8 + c, per-wave)
#pragma unroll
      for (int s = 0; s < 2; ++s) {
        const int chp = ((s * 4 + quad) ^ (c16 & 7)) * 8;
        bf16x8 ap = *(const bf16x8*)&pw[c16 * 64 + chp];
#pragma unroll
        for (int jd = 0; jd < 8; ++jd) {
          bf16x8 bv = *(const bf16x8*)&vsm[(jd * 16 + c16) * 64 + chp];
          o[jd] = __builtin_amdgcn_mfma_f32_16x16x32_bf16(ap, bv, o[jd], 0, 0, 0);
        }
      }
      asm volatile("s_barrier" ::: "memory");  // WAR fence for next staging
    }
#undef STAGE_KV

    // epilogue: single cross-lane lrow reduce, normalize, write att
    const int b = bh >> 4, h = bh & 15;
    float ri[4];
#pragma unroll
    for (int r = 0; r < 4; ++r) {
      float s = lrow[r];
      s += __shfl_xor(s, 1, 64);
      s += __shfl_xor(s, 2, 64);
      s += __shfl_xor(s, 4, 64);
      s += __shfl_xor(s, 8, 64);
      ri[r] = 1.f / s;
    }
#pragma unroll
    for (int jd = 0; jd < 8; ++jd)
#pragma unroll
      for (int r = 0; r < 4; ++r) {
        int t = q0 + wave * 16 + quad * 4 + r;
        att[(b * TDIM + t) * CDIM + h * DDIM + jd * 16 + c16] = f2b(o[jd][r] * ri[r]);
      }
    __syncthreads();  // before hv=1 re-stages Q over buf0
  }
}

// ---------- launcher ----------
extern "C" void kernel_launch(void* const* d_in, const int* in_sizes, int n_in,
                              void* d_out, int out_size, void* d_ws, size_t ws_size,
                              hipStream_t stream) {
  (void)in_sizes; (void)n_in; (void)out_size; (void)ws_size;
  const float* x      = (const float*)d_in[0];
  const float* w_qkv  = (const float*)d_in[1];
  const float* w_proj = (const float*)d_in[2];
  float* out  = (float*)d_out;
  float* kout = out + 16777216;
  float* vout = out + 2 * 16777216;

  char* ws = (char*)d_ws;
  u16*   xb     = (u16*)(ws);                   // 33.5 MB (reused as att)
  u16*   wqkvT  = (u16*)(ws + 33554432);        // 25.2 MB
  u16*   wprojT = (u16*)(ws + 58720256);        // 8.4 MB
  float* cosT   = (float*)(ws + 67108864);      // 0.5 MB
  float* sinT   = (float*)(ws + 67633152);      // 0.5 MB
  u16*   qb     = (u16*)(ws + 68157440);        // 33.5 MB
  u16*   kb     = (u16*)(ws + 101711872);       // 33.5 MB
  u16*   vt     = (u16*)(ws + 135266304);       // 33.5 MB  (total ~169 MB)
  u16*   att    = xb;

  static int attr_set = 0;
  if (!attr_set) {
    hipFuncSetAttribute((const void*)gemm_qkv,
                        hipFuncAttributeMaxDynamicSharedMemorySize, 131072);
    hipFuncSetAttribute((const void*)gemm_proj,
                        hipFuncAttributeMaxDynamicSharedMemorySize, 131072);
    hipFuncSetAttribute((const void*)attn,
                        hipFuncAttributeMaxDynamicSharedMemorySize, 81920);
    attr_set = 1;
  }

  convert_x<<<16384, 256, 0, stream>>>(x, xb, 4194304);
  transpose_w<<<dim3(192, 64), 256, 0, stream>>>(w_qkv, wqkvT, KK, N1);
  transpose_w<<<dim3(64, 64), 256, 0, stream>>>(w_proj, wprojT, KK, CDIM);
  rope_tab<<<512, 256, 0, stream>>>(cosT, sinT);
  gemm_qkv<<<dim3(24, 32), 512, 131072, stream>>>(xb, wqkvT, cosT, sinT, qb, kb, kout, vout, vt);
  attn<<<dim3(8, 64), 512, 81920, stream>>>(qb, kb, vt, att);
  gemm_proj<<<dim3(8, 32), 512, 131072, stream>>>(att, wprojT, out);
}

// Round 16
// 681.102 us; speedup vs baseline: 1.0182x; 1.0182x over previous
//
#include <hip/hip_runtime.h>
#include <math.h>

#define CDIM 2048
#define TDIM 2048
#define BDIM 4
#define HDIM 16
#define DDIM 128
#define M1   (BDIM * TDIM)   // 8192
#define N1   (3 * CDIM)      // 6144
#define KK   CDIM            // 2048
#define NT   32              // K tiles of 64

typedef unsigned short u16;
typedef __bf16 bf16x8 __attribute__((ext_vector_type(8)));
typedef float f32x4 __attribute__((ext_vector_type(4)));

// ---------- helpers ----------
__device__ __forceinline__ u16 f2b(float f) {
  union { float f; unsigned u; } x; x.f = f;
  unsigned r = x.u + 0x7fffu + ((x.u >> 16) & 1u);
  return (u16)(r >> 16);
}

__device__ __forceinline__ void gload_lds16(const void* g, void* l) {
  __builtin_amdgcn_global_load_lds(
      (__attribute__((address_space(1))) void*)g,
      (__attribute__((address_space(3))) void*)l, 16, 0, 0);
}

// ---------- fused prep kernel: convert_x + transpose_w(qkv) +
// transpose_w(proj) + rope_tab in ONE launch (block-range dispatch).
// Block budget: [0,16384) convert_x; [16384,28672) w_qkv T (192x64);
// [28672,32768) w_proj T (64x64); [32768,33280) rope_tab.
__global__ void prep(const float* __restrict__ x, u16* __restrict__ xb,
                     const float* __restrict__ w_qkv, u16* __restrict__ wqkvT,
                     const float* __restrict__ w_proj, u16* __restrict__ wprojT,
                     float* __restrict__ cosT, float* __restrict__ sinT) {
  __shared__ float tile[32][33];
  const int gb = blockIdx.x;
  if (gb < 16384) {
    int i = gb * 256 + threadIdx.x;
    float4 v = ((const float4*)x)[i];
    unsigned long long o = (unsigned long long)f2b(v.x)
                         | ((unsigned long long)f2b(v.y) << 16)
                         | ((unsigned long long)f2b(v.z) << 32)
                         | ((unsigned long long)f2b(v.w) << 48);
    ((unsigned long long*)xb)[i] = o;
  } else if (gb < 32768) {
    const float* w; u16* wt; int N, r;
    if (gb < 28672) { w = w_qkv;  wt = wqkvT;  N = N1;   r = gb - 16384; }
    else            { w = w_proj; wt = wprojT; N = CDIM; r = gb - 28672; }
    const int nblk = N >> 5;
    const int n0 = (r % nblk) * 32, k0 = (r / nblk) * 32;
    const int tx = threadIdx.x & 31, ty = threadIdx.x >> 5;
    for (int rr = ty; rr < 32; rr += 8)
      tile[rr][tx] = w[(k0 + rr) * N + n0 + tx];
    __syncthreads();
    for (int rr = ty; rr < 32; rr += 8)
      wt[(n0 + rr) * KK + k0 + tx] = f2b(tile[tx][rr]);
  } else {
    int i = (gb - 32768) * 256 + threadIdx.x;   // 0 .. 2048*64-1
    int t = i >> 6, d = i & 63;
    float inv = exp2f(-(float)d * (13.287712379549449f / 64.0f));
    float a = (float)t * inv;
    cosT[i] = cosf(a);
    sinT[i] = sinf(a);
  }
}

// =====================================================================
// 256x256-tile, BK=64, 8-wave (2Mx4N) GEMM — R5 schedule (best measured:
// ~227 us gemm_qkv, MfmaUtil 39% = the ~900 TF 2-barrier-structure
// ceiling). Quadrant-pipelined K-tile; 2 barriers + 2 counted vmcnt/tile.
// =====================================================================

#define VMW4 asm volatile("s_waitcnt vmcnt(4)" ::: "memory");
#define VMW2 asm volatile("s_waitcnt vmcnt(2)" ::: "memory");
#define VMW0 asm volatile("s_waitcnt vmcnt(0)" ::: "memory");
#define NOWAIT

#define GEMM256_TILE(bufA_, bufB_, nA_, nB_, kno_, STG, WMID, WEND)            \
  {                                                                            \
    __builtin_amdgcn_s_barrier();  /* publishes A-lo,B-lo,B-hi(t); WAR */      \
    bf16x8 aX[4][2], aY[4][2], bX[2][2], bY[2][2];                             \
    /* q0 frags: A-lo, B-lo */                                                 \
    _Pragma("unroll")                                                          \
    for (int i = 0; i < 4; ++i)                                                \
      _Pragma("unroll")                                                        \
      for (int kh = 0; kh < 2; ++kh)                                           \
        aX[i][kh] = *(const bf16x8*)&(bufA_)[aoff + i * 1024 +                 \
                                             (((kh * 4 + quad) ^ rsw) * 8)];   \
    _Pragma("unroll")                                                          \
    for (int j = 0; j < 2; ++j)                                                \
      _Pragma("unroll")                                                        \
      for (int kh = 0; kh < 2; ++kh)                                           \
        bX[j][kh] = *(const bf16x8*)&(bufB_)[boff + j * 1024 +                 \
                                             (((kh * 4 + quad) ^ rsw) * 8)];   \
    /* q0: m-lo x n-lo */                                                      \
    __builtin_amdgcn_s_setprio(1);                                             \
    _Pragma("unroll")                                                          \
    for (int i = 0; i < 4; ++i)                                                \
      _Pragma("unroll")                                                        \
      for (int j = 0; j < 2; ++j)                                              \
        _Pragma("unroll")                                                      \
        for (int kh = 0; kh < 2; ++kh)                                         \
          acc[i][j] = __builtin_amdgcn_mfma_f32_16x16x32_bf16(                 \
              aX[i][kh], bX[j][kh], acc[i][j], 0, 0, 0);                       \
    __builtin_amdgcn_s_setprio(0);                                             \
    /* pre-read q1 frags: B-hi (headroom: stage + vmcnt + barrier) */          \
    _Pragma("unroll")                                                          \
    for (int j = 0; j < 2; ++j)                                                \
      _Pragma("unroll")                                                        \
      for (int kh = 0; kh < 2; ++kh)                                           \
        bY[j][kh] = *(const bf16x8*)&(bufB_)[8192 + boff + j * 1024 +          \
                                             (((kh * 4 + quad) ^ rsw) * 8)];   \
    if (STG) {                                                                 \
      _Pragma("unroll")                                                        \
      for (int q = 0; q < 2; ++q)                                              \
        gload_lds16(AgBase + (q * 128) * KK + (kno_), &(nA_)[q * 4096 + ldsw]);\
      _Pragma("unroll")                                                        \
      for (int q = 0; q < 2; ++q)                                              \
        gload_lds16(BgBase + (q * 128) * KK + (kno_),                          \
                    &(nB_)[q * 4096 + ldsw]);                                  \
    }                                                                          \
    WMID                                                                       \
    __builtin_amdgcn_s_barrier();  /* publishes A-hi(t) */                     \
    /* q1: m-lo x n-hi (aX, bY already in regs) */                             \
    __builtin_amdgcn_s_setprio(1);                                             \
    _Pragma("unroll")                                                          \
    for (int i = 0; i < 4; ++i)                                                \
      _Pragma("unroll")                                                        \
      for (int j = 0; j < 2; ++j)                                              \
        _Pragma("unroll")                                                      \
        for (int kh = 0; kh < 2; ++kh)                                         \
          acc[i][2 + j] = __builtin_amdgcn_mfma_f32_16x16x32_bf16(             \
              aX[i][kh], bY[j][kh], acc[i][2 + j], 0, 0, 0);                   \
    __builtin_amdgcn_s_setprio(0);                                             \
    /* pre-read q2 frags: A-hi (headroom: one MFMA cluster + stage) */         \
    _Pragma("unroll")                                                          \
    for (int i = 0; i < 4; ++i)                                                \
      _Pragma("unroll")                                                        \
      for (int kh = 0; kh < 2; ++kh)                                           \
        aY[i][kh] = *(const bf16x8*)&(bufA_)[8192 + aoff + i * 1024 +          \
                                             (((kh * 4 + quad) ^ rsw) * 8)];   \
    if (STG) {                                                                 \
      _Pragma("unroll")                                                        \
      for (int q = 0; q < 2; ++q)                                              \
        gload_lds16(BgBase + (q * 128 + 32) * KK + (kno_),                     \
                    &(nB_)[8192 + q * 4096 + ldsw]);                           \
    }                                                                          \
    /* q2: m-hi x n-hi */                                                      \
    __builtin_amdgcn_s_setprio(1);                                             \
    _Pragma("unroll")                                                          \
    for (int i = 0; i < 4; ++i)                                                \
      _Pragma("unroll")                                                        \
      for (int j = 0; j < 2; ++j)                                              \
        _Pragma("unroll")                                                      \
        for (int kh = 0; kh < 2; ++kh)                                         \
          acc[4 + i][2 + j] = __builtin_amdgcn_mfma_f32_16x16x32_bf16(         \
              aY[i][kh], bY[j][kh], acc[4 + i][2 + j], 0, 0, 0);               \
    __builtin_amdgcn_s_setprio(0);                                             \
    if (STG) {                                                                 \
      _Pragma("unroll")                                                        \
      for (int q = 0; q < 2; ++q)                                              \
        gload_lds16(AgBase + (q * 128 + 64) * KK + (kno_),                     \
                    &(nA_)[8192 + q * 4096 + ldsw]);                           \
    }                                                                          \
    /* q3: m-hi x n-lo (aY, bX already in regs — no re-read) */                \
    __builtin_amdgcn_s_setprio(1);                                             \
    _Pragma("unroll")                                                          \
    for (int i = 0; i < 4; ++i)                                                \
      _Pragma("unroll")                                                        \
      for (int j = 0; j < 2; ++j)                                              \
        _Pragma("unroll")                                                      \
        for (int kh = 0; kh < 2; ++kh)                                         \
          acc[4 + i][j] = __builtin_amdgcn_mfma_f32_16x16x32_bf16(             \
              aY[i][kh], bX[j][kh], acc[4 + i][j], 0, 0, 0);                   \
    __builtin_amdgcn_s_setprio(0);                                             \
    WEND                                                                       \
  }

#define GEMM256_MAINLOOP(APTR, BPTR)                                           \
  const int rA = lane >> 3, cA = lane & 7;                                     \
  const int w8r = wave * 8 + rA;                                               \
  const int swz8 = (cA ^ rA) * 8;                                              \
  const u16* AgBase = (APTR) + (m0 + w8r) * KK + swz8;                         \
  const int nb = ((w8r >> 5) * 64) + (w8r & 31);                               \
  const u16* BgBase = (BPTR) + (n0 + nb) * KK + swz8;                          \
  const int ldsw = wave * 512;                                                 \
  const int rsw = c16 & 7;                                                     \
  const int aoff = (((wave >> 2) * 64) + c16) * 64;                            \
  const int boff = (((wave & 3) * 32) + c16) * 64;                             \
  f32x4 acc[8][4];                                                             \
  {                                                                            \
    f32x4 z = {0.f, 0.f, 0.f, 0.f};                                            \
    _Pragma("unroll")                                                          \
    for (int i = 0; i < 8; ++i)                                                \
      _Pragma("unroll")                                                        \
      for (int j = 0; j < 4; ++j) acc[i][j] = z;                               \
  }                                                                            \
  /* prologue: stage tile 0 (A-lo, B-lo, B-hi, A-hi); keep A-hi in flight */   \
  _Pragma("unroll")                                                            \
  for (int q = 0; q < 2; ++q)                                                  \
    gload_lds16(AgBase + (q * 128) * KK, &lds[q * 4096 + ldsw]);               \
  _Pragma("unroll")                                                            \
  for (int q = 0; q < 2; ++q)                                                  \
    gload_lds16(BgBase + (q * 128) * KK, &lds[32768 + q * 4096 + ldsw]);       \
  _Pragma("unroll")                                                            \
  for (int q = 0; q < 2; ++q)                                                  \
    gload_lds16(BgBase + (q * 128 + 32) * KK,                                  \
                &lds[32768 + 8192 + q * 4096 + ldsw]);                         \
  _Pragma("unroll")                                                            \
  for (int q = 0; q < 2; ++q)                                                  \
    gload_lds16(AgBase + (q * 128 + 64) * KK, &lds[8192 + q * 4096 + ldsw]);   \
  VMW2                                                                         \
  for (int kt = 0; kt < NT - 1; ++kt) {                                        \
    const int cur = kt & 1;                                                    \
    const u16* bA = &lds[cur * 16384];                                         \
    const u16* bB = &lds[32768 + cur * 16384];                                 \
    u16* nA = &lds[(cur ^ 1) * 16384];                                         \
    u16* nB = &lds[32768 + (cur ^ 1) * 16384];                                 \
    const int kno = (kt + 1) * 64;                                             \
    GEMM256_TILE(bA, bB, nA, nB, kno, 1, VMW4, VMW2)                           \
  }                                                                            \
  /* tail tile NT-1 (odd -> buf1): no staging; mid wait drains A-hi */         \
  GEMM256_TILE((&lds[16384]), (&lds[32768 + 16384]), (&lds[0]),                \
               (&lds[32768]), 0, 0, VMW0, NOWAIT)

// ---------- GEMM1: qkv = x @ w_qkv, epilogue: rope + scatter + fused V^T ----
__global__ __launch_bounds__(512, 1) void gemm_qkv(
    const u16* __restrict__ A,    // xb [8192][2048]
    const u16* __restrict__ Bt,   // wqkvT [6144][2048]
    const float* __restrict__ cosT, const float* __restrict__ sinT,
    u16* __restrict__ qb, u16* __restrict__ kb,
    float* __restrict__ kout, float* __restrict__ vout,
    u16* __restrict__ vtout)
{
  extern __shared__ __align__(16) u16 lds[];   // 131072 B
  const int tid = threadIdx.x, wave = tid >> 6, lane = tid & 63;
  const int quad = lane >> 4, c16 = lane & 15;
  // bijective XCD swizzle: nwg = 24*32 = 768, 768 % 8 == 0, cpx = 96
  const int bid = blockIdx.y * 24 + blockIdx.x;
  const int swz = (bid & 7) * 96 + (bid >> 3);
  const int m0 = (swz / 24) * 256, n0 = (swz % 24) * 256;

  GEMM256_MAINLOOP(A, Bt)

  // ---- epilogue: rope + scatter, 4 passes of 64 rows through LDS ----
  // NOTE: pass loop MUST be fully unrolled — acc[] indexed by pass-derived
  // values; runtime indexing would demote acc to scratch (rule #20, R2 bug).
  float* cbuf = (float*)lds;                  // [64][261] fp32 = 66.8 KB
  const int mat = n0 >> 11;                   // 0=q, 1=k, 2=v (block-uniform)
  const int hbase = (n0 & 2047) >> 7;
  // 1/sqrt(128) * log2(e) folded into q (attn uses exp2)
  const float qscale = 0.1275178689414753f;
#pragma unroll
  for (int pass = 0; pass < 4; ++pass) {
    __syncthreads();
    if ((wave >> 2) == (pass >> 1)) {
#pragma unroll
      for (int i = 0; i < 4; ++i) {
        const int mf = (pass & 1) * 4 + i;
#pragma unroll
        for (int j = 0; j < 4; ++j)
#pragma unroll
          for (int r = 0; r < 4; ++r)
            cbuf[(i * 16 + quad * 4 + r) * 261 + (wave & 3) * 64 + j * 16 + c16] = acc[mf][j][r];
      }
    }
    __syncthreads();
#pragma unroll
    for (int it = 0; it < 16; ++it) {
      int p = it * 512 + tid;          // 0..8191
      int lr = p >> 7;                 // local row 0..63
      int hc = (p >> 6) & 1;           // head-chunk within 256-wide tile
      int d = p & 63;
      float x1 = cbuf[lr * 261 + hc * 128 + d];
      float x2 = cbuf[lr * 261 + hc * 128 + 64 + d];
      int mg = m0 + pass * 64 + lr;
      int b = mg >> 11, t = mg & 2047;
      int h = hbase + hc;
      int idx = ((b * HDIM + h) * TDIM + t) * DDIM + d;
      if (mat == 2) {
        vout[idx] = x1; vout[idx + 64] = x2;
      } else {
        float cs = cosT[t * 64 + d], sn = sinT[t * 64 + d];
        float o1 = x1 * cs - x2 * sn;
        float o2 = x1 * sn + x2 * cs;
        if (mat == 0) {
          qb[idx] = f2b(o1 * qscale); qb[idx + 64] = f2b(o2 * qscale);
        } else {
          kout[idx] = o1; kout[idx + 64] = o2;
          kb[idx] = f2b(o1); kb[idx + 64] = f2b(o2);
        }
      }
    }
    // fused V^T: vt[bh][d][t] bf16, coalesced along t (replaces transpose_v)
    if (mat == 2) {
#pragma unroll
      for (int it = 0; it < 16; ++it) {
        int p = it * 512 + tid;        // 0..8191
        int tl = p & 63;               // t_local (lanes 0-63 share column)
        int c2 = p >> 6;               // 0..127  (d within head)
        float xA = cbuf[tl * 261 + c2];
        float xB = cbuf[tl * 261 + 128 + c2];
        int mg = m0 + pass * 64 + tl;
        int b = mg >> 11, t = mg & 2047;
        vtout[((b * HDIM + hbase) * DDIM + c2) * TDIM + t] = f2b(xA);
        vtout[((b * HDIM + hbase + 1) * DDIM + c2) * TDIM + t] = f2b(xB);
      }
    }
  }
}

// ---------- GEMM2: out = att @ w_proj ----------
__global__ __launch_bounds__(512, 1) void gemm_proj(
    const u16* __restrict__ A,    // att [8192][2048]
    const u16* __restrict__ Bt,   // wprojT [2048][2048]
    float* __restrict__ out)
{
  extern __shared__ __align__(16) u16 lds[];   // 131072 B
  const int tid = threadIdx.x, wave = tid >> 6, lane = tid & 63;
  const int quad = lane >> 4, c16 = lane & 15;
  // bijective XCD swizzle: nwg = 8*32 = 256, cpx = 32
  const int bid = blockIdx.y * 8 + blockIdx.x;
  const int swz = (bid & 7) * 32 + (bid >> 3);
  const int m0 = (swz >> 3) * 256, n0 = (swz & 7) * 256;

  GEMM256_MAINLOOP(A, Bt)

  const int wm = (wave >> 2) * 128, wn = (wave & 3) * 64;
#pragma unroll
  for (int mf = 0; mf < 8; ++mf)
#pragma unroll
    for (int nf = 0; nf < 4; ++nf)
#pragma unroll
      for (int r = 0; r < 4; ++r)
        out[(m0 + wm + mf * 16 + quad * 4 + r) * CDIM + n0 + wn + nf * 16 + c16] =
            acc[mf][nf][r];
}

// ---------- flash attention: 8-wave blocks, paired tiles, dbuf K/V ----------
// R14 exact (best measured E2E 689): 512 threads / 8 waves, each wave owns
// one 16-row q-group; paired tiles (bx+8, 7-bx) = 34 chunks/block; 2
// blocks/CU x 8 waves = 4 waves/SIMD; static-max softmax (log2 domain,
// M=8); counted-vmcnt double-buffered K/V (mid vmcnt(4), tail vmcnt(0)).
// LDS 80 KB: buf0 K[0,8192) V[8192,16384); buf1 [16384,32768);
//            P [32768,40960) — per-wave 1024 u16.
__global__ __launch_bounds__(512, 4) void attn(
    const u16* __restrict__ qb, const u16* __restrict__ kb,
    const u16* __restrict__ vt, u16* __restrict__ att)
{
  extern __shared__ __align__(16) u16 sh[];   // 81920 B dynamic
  u16* const psm = sh + 32768;        // per-wave 1024 u16 P buffer

  const int tid = threadIdx.x, wave = tid >> 6, lane = tid & 63;
  const int quad = lane >> 4, c16 = lane & 15;
  const int bx = blockIdx.x;          // 0..7 (pair slot)
  const int bh = blockIdx.y;          // 0..63

  // staging lane constants
  const int rlK = wave * 4 + (lane >> 4), chK = lane & 15;   // K/Q: 4-row strips
  const int rlV = wave * 8 + (lane >> 3), chV = lane & 7;    // V: 8-row strips

  for (int hv = 0; hv < 2; ++hv) {
    const int qt = hv ? (7 - bx) : (bx + 8);   // heavy tile first; 34 chunks total
    const int q0 = qt * 128;

    // ---- stage Q (128x128) into sh[0,16384) u16 (32 KB), extract frags ----
    {
      const u16* qg = qb + (bh * TDIM + q0) * DDIM;
#pragma unroll
      for (int r = 0; r < 4; ++r) {
        int row = r * 32 + rlK;
        gload_lds16(qg + row * DDIM + (chK ^ (row & 15)) * 8,
                    &sh[(r * 32 + wave * 4) * 128]);
      }
    }
    __syncthreads();
    bf16x8 qf[4];
#pragma unroll
    for (int kp = 0; kp < 4; ++kp)
      qf[kp] = *(const bf16x8*)&sh[(wave * 16 + c16) * 128 +
                                   (((kp * 4 + quad) ^ c16) * 8)];
    __syncthreads();   // all waves done reading Q area -> reusable for K/V

    f32x4 o[8];
    f32x4 zero = {0.f, 0.f, 0.f, 0.f};
#pragma unroll
    for (int jd = 0; jd < 8; ++jd) o[jd] = zero;
    float lrow[4];
#pragma unroll
    for (int r = 0; r < 4; ++r) lrow[r] = 0.f;

    const int nchunk = 2 * qt + 2;

#define STAGE_KV(kcs, bufbase)                                                 \
    {                                                                          \
      const int kcs0 = (kcs) * 64;                                             \
      const u16* kg = kb + (bh * TDIM + kcs0) * DDIM;                          \
      _Pragma("unroll")                                                        \
      for (int r = 0; r < 2; ++r) {                                            \
        int row = r * 32 + rlK;                                                \
        gload_lds16(kg + row * DDIM + (chK ^ (row & 15)) * 8,                  \
                    &sh[(bufbase) + (r * 32 + wave * 4) * 128]);               \
      }                                                                        \
      const u16* vg = vt + bh * (DDIM * TDIM) + kcs0;                          \
      _Pragma("unroll")                                                        \
      for (int r = 0; r < 2; ++r) {                                            \
        int row = r * 64 + rlV;                                                \
        gload_lds16(vg + row * TDIM + (chV ^ (row & 7)) * 8,                   \
                    &sh[(bufbase) + 8192 + (r * 64 + wave * 8) * 64]);         \
      }                                                                        \
    }

    // prologue: stage chunk 0 into buf0 (4 loads/thread outstanding)
    STAGE_KV(0, 0)

    for (int kc = 0; kc < nchunk; ++kc) {
      const int kc0 = kc * 64;
      const int cur = kc & 1;
      const u16* ksm = sh + cur * 16384;
      const u16* vsm = ksm + 8192;

      // issue next chunk's staging into buf^1 (WAR-safe: its readers
      // finished before the end-barrier of iteration kc-1)
      if (kc + 1 < nchunk) {
        STAGE_KV(kc + 1, (cur ^ 1) * 16384)
        asm volatile("s_waitcnt vmcnt(4)" ::: "memory");  // completes kc's 4
      } else {
        asm volatile("s_waitcnt vmcnt(0)" ::: "memory");  // drain last
      }
      asm volatile("s_barrier" ::: "memory");             // publish chunk kc

      // S = Q K^T (log2-domain: scale*log2e pre-folded into Q)
      f32x4 st[4];
#pragma unroll
      for (int j = 0; j < 4; ++j) st[j] = zero;
#pragma unroll
      for (int kp = 0; kp < 4; ++kp) {
#pragma unroll
        for (int j = 0; j < 4; ++j) {
          bf16x8 bk = *(const bf16x8*)&ksm[(j * 16 + c16) * 128 +
                                           (((kp * 4 + quad) ^ c16) * 8)];
          st[j] = __builtin_amdgcn_mfma_f32_16x16x32_bf16(qf[kp], bk, st[j], 0, 0, 0);
        }
      }

      // static-max softmax: P = exp2(S - 8); no max tracking, no rescale,
      // no cross-lane reduce here (lrow partial per lane; reduced at end).
      u16* const pw = psm + wave * 1024;
      const bool dg = (kc0 + 63 > q0 + wave * 16);
      const int qrow_base = q0 + wave * 16 + quad * 4;
#pragma unroll
      for (int r = 0; r < 4; ++r) {
        const int row16 = quad * 4 + r;
        float sum = 0.f;
#pragma unroll
        for (int j = 0; j < 4; ++j) {
          float sv = st[j][r];
          if (dg && (kc0 + j * 16 + c16 > qrow_base + r)) sv = -INFINITY;
          float p = exp2f(sv - 8.0f);
          sum += p;
          int chunk = (j * 2 + (c16 >> 3)) ^ (row16 & 7);
          pw[row16 * 64 + chunk * 8 + (c16 & 7)] = f2b(p);
        }
        lrow[r] += sum;
      }

      asm volatile("s_waitcnt lgkmcnt(0)" ::: "memory");

      // O += P V   (P layout: row16*64 + chunk*8 + c, per-wave)
#pragma unroll
      for (int s = 0; s < 2; ++s) {
        const int chp = ((s * 4 + quad) ^ (c16 & 7)) * 8;
        bf16x8 ap = *(const bf16x8*)&pw[c16 * 64 + chp];
#pragma unroll
        for (int jd = 0; jd < 8; ++jd) {
          bf16x8 bv = *(const bf16x8*)&vsm[(jd * 16 + c16) * 64 + chp];
          o[jd] = __builtin_amdgcn_mfma_f32_16x16x32_bf16(ap, bv, o[jd], 0, 0, 0);
        }
      }
      asm volatile("s_barrier" ::: "memory");  // WAR fence for next staging
    }
#undef STAGE_KV

    // epilogue: single cross-lane lrow reduce, normalize, write att
    const int b = bh >> 4, h = bh & 15;
    float ri[4];
#pragma unroll
    for (int r = 0; r < 4; ++r) {
      float s = lrow[r];
      s += __shfl_xor(s, 1, 64);
      s += __shfl_xor(s, 2, 64);
      s += __shfl_xor(s, 4, 64);
      s += __shfl_xor(s, 8, 64);
      ri[r] = 1.f / s;
    }
#pragma unroll
    for (int jd = 0; jd < 8; ++jd)
#pragma unroll
      for (int r = 0; r < 4; ++r) {
        int t = q0 + wave * 16 + quad * 4 + r;
        att[(b * TDIM + t) * CDIM + h * DDIM + jd * 16 + c16] = f2b(o[jd][r] * ri[r]);
      }
    __syncthreads();  // before hv=1 re-stages Q over buf0
  }
}

// ---------- launcher ----------
extern "C" void kernel_launch(void* const* d_in, const int* in_sizes, int n_in,
                              void* d_out, int out_size, void* d_ws, size_t ws_size,
                              hipStream_t stream) {
  (void)in_sizes; (void)n_in; (void)out_size; (void)ws_size;
  const float* x      = (const float*)d_in[0];
  const float* w_qkv  = (const float*)d_in[1];
  const float* w_proj = (const float*)d_in[2];
  float* out  = (float*)d_out;
  float* kout = out + 16777216;
  float* vout = out + 2 * 16777216;

  char* ws = (char*)d_ws;
  u16*   xb     = (u16*)(ws);                   // 33.5 MB (reused as att)
  u16*   wqkvT  = (u16*)(ws + 33554432);        // 25.2 MB
  u16*   wprojT = (u16*)(ws + 58720256);        // 8.4 MB
  float* cosT   = (float*)(ws + 67108864);      // 0.5 MB
  float* sinT   = (float*)(ws + 67633152);      // 0.5 MB
  u16*   qb     = (u16*)(ws + 68157440);        // 33.5 MB
  u16*   kb     = (u16*)(ws + 101711872);       // 33.5 MB
  u16*   vt     = (u16*)(ws + 135266304);       // 33.5 MB  (total ~169 MB)
  u16*   att    = xb;

  static int attr_set = 0;
  if (!attr_set) {
    hipFuncSetAttribute((const void*)gemm_qkv,
                        hipFuncAttributeMaxDynamicSharedMemorySize, 131072);
    hipFuncSetAttribute((const void*)gemm_proj,
                        hipFuncAttributeMaxDynamicSharedMemorySize, 131072);
    hipFuncSetAttribute((const void*)attn,
                        hipFuncAttributeMaxDynamicSharedMemorySize, 81920);
    attr_set = 1;
  }

  prep<<<33280, 256, 0, stream>>>(x, xb, w_qkv, wqkvT, w_proj, wprojT, cosT, sinT);
  gemm_qkv<<<dim3(24, 32), 512, 131072, stream>>>(xb, wqkvT, cosT, sinT, qb, kb, kout, vout, vt);
  attn<<<dim3(8, 64), 512, 81920, stream>>>(qb, kb, vt, att);
  gemm_proj<<<dim3(8, 32), 512, 131072, stream>>>(att, wprojT, out);
}

// Round 17
// 673.136 us; speedup vs baseline: 1.0303x; 1.0118x over previous
//
#include <hip/hip_runtime.h>
#include <math.h>

#define CDIM 2048
#define TDIM 2048
#define BDIM 4
#define HDIM 16
#define DDIM 128
#define M1   (BDIM * TDIM)   // 8192
#define N1   (3 * CDIM)      // 6144
#define KK   CDIM            // 2048
#define NT   32              // K tiles of 64

typedef unsigned short u16;
typedef __bf16 bf16x8 __attribute__((ext_vector_type(8)));
typedef float f32x4 __attribute__((ext_vector_type(4)));

// ---------- helpers ----------
__device__ __forceinline__ u16 f2b(float f) {
  union { float f; unsigned u; } x; x.f = f;
  unsigned r = x.u + 0x7fffu + ((x.u >> 16) & 1u);
  return (u16)(r >> 16);
}

__device__ __forceinline__ void gload_lds16(const void* g, void* l) {
  __builtin_amdgcn_global_load_lds(
      (__attribute__((address_space(1))) void*)g,
      (__attribute__((address_space(3))) void*)l, 16, 0, 0);
}

// ---------- fused prep kernel (R16, verified): convert_x + transpose_w x2 +
// rope_tab in ONE launch. Blocks: [0,16384) convert_x; [16384,28672) w_qkv;
// [28672,32768) w_proj; [32768,33280) rope_tab.
__global__ void prep(const float* __restrict__ x, u16* __restrict__ xb,
                     const float* __restrict__ w_qkv, u16* __restrict__ wqkvT,
                     const float* __restrict__ w_proj, u16* __restrict__ wprojT,
                     float* __restrict__ cosT, float* __restrict__ sinT) {
  __shared__ float tile[32][33];
  const int gb = blockIdx.x;
  if (gb < 16384) {
    int i = gb * 256 + threadIdx.x;
    float4 v = ((const float4*)x)[i];
    unsigned long long o = (unsigned long long)f2b(v.x)
                         | ((unsigned long long)f2b(v.y) << 16)
                         | ((unsigned long long)f2b(v.z) << 32)
                         | ((unsigned long long)f2b(v.w) << 48);
    ((unsigned long long*)xb)[i] = o;
  } else if (gb < 32768) {
    const float* w; u16* wt; int N, r;
    if (gb < 28672) { w = w_qkv;  wt = wqkvT;  N = N1;   r = gb - 16384; }
    else            { w = w_proj; wt = wprojT; N = CDIM; r = gb - 28672; }
    const int nblk = N >> 5;
    const int n0 = (r % nblk) * 32, k0 = (r / nblk) * 32;
    const int tx = threadIdx.x & 31, ty = threadIdx.x >> 5;
    for (int rr = ty; rr < 32; rr += 8)
      tile[rr][tx] = w[(k0 + rr) * N + n0 + tx];
    __syncthreads();
    for (int rr = ty; rr < 32; rr += 8)
      wt[(n0 + rr) * KK + k0 + tx] = f2b(tile[tx][rr]);
  } else {
    int i = (gb - 32768) * 256 + threadIdx.x;   // 0 .. 2048*64-1
    int t = i >> 6, d = i & 63;
    float inv = exp2f(-(float)d * (13.287712379549449f / 64.0f));
    float a = (float)t * inv;
    cosT[i] = cosf(a);
    sinT[i] = sinf(a);
  }
}

// =====================================================================
// 256x256-tile, BK=64, 8-wave (2Mx4N) GEMM — R5 schedule (best measured).
// =====================================================================

#define VMW4 asm volatile("s_waitcnt vmcnt(4)" ::: "memory");
#define VMW2 asm volatile("s_waitcnt vmcnt(2)" ::: "memory");
#define VMW0 asm volatile("s_waitcnt vmcnt(0)" ::: "memory");
#define NOWAIT

#define GEMM256_TILE(bufA_, bufB_, nA_, nB_, kno_, STG, WMID, WEND)            \
  {                                                                            \
    __builtin_amdgcn_s_barrier();  /* publishes A-lo,B-lo,B-hi(t); WAR */      \
    bf16x8 aX[4][2], aY[4][2], bX[2][2], bY[2][2];                             \
    /* q0 frags: A-lo, B-lo */                                                 \
    _Pragma("unroll")                                                          \
    for (int i = 0; i < 4; ++i)                                                \
      _Pragma("unroll")                                                        \
      for (int kh = 0; kh < 2; ++kh)                                           \
        aX[i][kh] = *(const bf16x8*)&(bufA_)[aoff + i * 1024 +                 \
                                             (((kh * 4 + quad) ^ rsw) * 8)];   \
    _Pragma("unroll")                                                          \
    for (int j = 0; j < 2; ++j)                                                \
      _Pragma("unroll")                                                        \
      for (int kh = 0; kh < 2; ++kh)                                           \
        bX[j][kh] = *(const bf16x8*)&(bufB_)[boff + j * 1024 +                 \
                                             (((kh * 4 + quad) ^ rsw) * 8)];   \
    /* q0: m-lo x n-lo */                                                      \
    __builtin_amdgcn_s_setprio(1);                                             \
    _Pragma("unroll")                                                          \
    for (int i = 0; i < 4; ++i)                                                \
      _Pragma("unroll")                                                        \
      for (int j = 0; j < 2; ++j)                                              \
        _Pragma("unroll")                                                      \
        for (int kh = 0; kh < 2; ++kh)                                         \
          acc[i][j] = __builtin_amdgcn_mfma_f32_16x16x32_bf16(                 \
              aX[i][kh], bX[j][kh], acc[i][j], 0, 0, 0);                       \
    __builtin_amdgcn_s_setprio(0);                                             \
    /* pre-read q1 frags: B-hi */                                              \
    _Pragma("unroll")                                                          \
    for (int j = 0; j < 2; ++j)                                                \
      _Pragma("unroll")                                                        \
      for (int kh = 0; kh < 2; ++kh)                                           \
        bY[j][kh] = *(const bf16x8*)&(bufB_)[8192 + boff + j * 1024 +          \
                                             (((kh * 4 + quad) ^ rsw) * 8)];   \
    if (STG) {                                                                 \
      _Pragma("unroll")                                                        \
      for (int q = 0; q < 2; ++q)                                              \
        gload_lds16(AgBase + (q * 128) * KK + (kno_), &(nA_)[q * 4096 + ldsw]);\
      _Pragma("unroll")                                                        \
      for (int q = 0; q < 2; ++q)                                              \
        gload_lds16(BgBase + (q * 128) * KK + (kno_),                          \
                    &(nB_)[q * 4096 + ldsw]);                                  \
    }                                                                          \
    WMID                                                                       \
    __builtin_amdgcn_s_barrier();  /* publishes A-hi(t) */                     \
    /* q1: m-lo x n-hi */                                                      \
    __builtin_amdgcn_s_setprio(1);                                             \
    _Pragma("unroll")                                                          \
    for (int i = 0; i < 4; ++i)                                                \
      _Pragma("unroll")                                                        \
      for (int j = 0; j < 2; ++j)                                              \
        _Pragma("unroll")                                                      \
        for (int kh = 0; kh < 2; ++kh)                                         \
          acc[i][2 + j] = __builtin_amdgcn_mfma_f32_16x16x32_bf16(             \
              aX[i][kh], bY[j][kh], acc[i][2 + j], 0, 0, 0);                   \
    __builtin_amdgcn_s_setprio(0);                                             \
    /* pre-read q2 frags: A-hi */                                              \
    _Pragma("unroll")                                                          \
    for (int i = 0; i < 4; ++i)                                                \
      _Pragma("unroll")                                                        \
      for (int kh = 0; kh < 2; ++kh)                                           \
        aY[i][kh] = *(const bf16x8*)&(bufA_)[8192 + aoff + i * 1024 +          \
                                             (((kh * 4 + quad) ^ rsw) * 8)];   \
    if (STG) {                                                                 \
      _Pragma("unroll")                                                        \
      for (int q = 0; q < 2; ++q)                                              \
        gload_lds16(BgBase + (q * 128 + 32) * KK + (kno_),                     \
                    &(nB_)[8192 + q * 4096 + ldsw]);                           \
    }                                                                          \
    /* q2: m-hi x n-hi */                                                      \
    __builtin_amdgcn_s_setprio(1);                                             \
    _Pragma("unroll")                                                          \
    for (int i = 0; i < 4; ++i)                                                \
      _Pragma("unroll")                                                        \
      for (int j = 0; j < 2; ++j)                                              \
        _Pragma("unroll")                                                      \
        for (int kh = 0; kh < 2; ++kh)                                         \
          acc[4 + i][2 + j] = __builtin_amdgcn_mfma_f32_16x16x32_bf16(         \
              aY[i][kh], bY[j][kh], acc[4 + i][2 + j], 0, 0, 0);               \
    __builtin_amdgcn_s_setprio(0);                                             \
    if (STG) {                                                                 \
      _Pragma("unroll")                                                        \
      for (int q = 0; q < 2; ++q)                                              \
        gload_lds16(AgBase + (q * 128 + 64) * KK + (kno_),                     \
                    &(nA_)[8192 + q * 4096 + ldsw]);                           \
    }                                                                          \
    /* q3: m-hi x n-lo */                                                      \
    __builtin_amdgcn_s_setprio(1);                                             \
    _Pragma("unroll")                                                          \
    for (int i = 0; i < 4; ++i)                                                \
      _Pragma("unroll")                                                        \
      for (int j = 0; j < 2; ++j)                                              \
        _Pragma("unroll")                                                      \
        for (int kh = 0; kh < 2; ++kh)                                         \
          acc[4 + i][j] = __builtin_amdgcn_mfma_f32_16x16x32_bf16(             \
              aY[i][kh], bX[j][kh], acc[4 + i][j], 0, 0, 0);                   \
    __builtin_amdgcn_s_setprio(0);                                             \
    WEND                                                                       \
  }

#define GEMM256_MAINLOOP(APTR, BPTR)                                           \
  const int rA = lane >> 3, cA = lane & 7;                                     \
  const int w8r = wave * 8 + rA;                                               \
  const int swz8 = (cA ^ rA) * 8;                                              \
  const u16* AgBase = (APTR) + (m0 + w8r) * KK + swz8;                         \
  const int nb = ((w8r >> 5) * 64) + (w8r & 31);                               \
  const u16* BgBase = (BPTR) + (n0 + nb) * KK + swz8;                          \
  const int ldsw = wave * 512;                                                 \
  const int rsw = c16 & 7;                                                     \
  const int aoff = (((wave >> 2) * 64) + c16) * 64;                            \
  const int boff = (((wave & 3) * 32) + c16) * 64;                             \
  f32x4 acc[8][4];                                                             \
  {                                                                            \
    f32x4 z = {0.f, 0.f, 0.f, 0.f};                                            \
    _Pragma("unroll")                                                          \
    for (int i = 0; i < 8; ++i)                                                \
      _Pragma("unroll")                                                        \
      for (int j = 0; j < 4; ++j) acc[i][j] = z;                               \
  }                                                                            \
  _Pragma("unroll")                                                            \
  for (int q = 0; q < 2; ++q)                                                  \
    gload_lds16(AgBase + (q * 128) * KK, &lds[q * 4096 + ldsw]);               \
  _Pragma("unroll")                                                            \
  for (int q = 0; q < 2; ++q)                                                  \
    gload_lds16(BgBase + (q * 128) * KK, &lds[32768 + q * 4096 + ldsw]);       \
  _Pragma("unroll")                                                            \
  for (int q = 0; q < 2; ++q)                                                  \
    gload_lds16(BgBase + (q * 128 + 32) * KK,                                  \
                &lds[32768 + 8192 + q * 4096 + ldsw]);                         \
  _Pragma("unroll")                                                            \
  for (int q = 0; q < 2; ++q)                                                  \
    gload_lds16(AgBase + (q * 128 + 64) * KK, &lds[8192 + q * 4096 + ldsw]);   \
  VMW2                                                                         \
  for (int kt = 0; kt < NT - 1; ++kt) {                                        \
    const int cur = kt & 1;                                                    \
    const u16* bA = &lds[cur * 16384];                                         \
    const u16* bB = &lds[32768 + cur * 16384];                                 \
    u16* nA = &lds[(cur ^ 1) * 16384];                                         \
    u16* nB = &lds[32768 + (cur ^ 1) * 16384];                                 \
    const int kno = (kt + 1) * 64;                                             \
    GEMM256_TILE(bA, bB, nA, nB, kno, 1, VMW4, VMW2)                           \
  }                                                                            \
  GEMM256_TILE((&lds[16384]), (&lds[32768 + 16384]), (&lds[0]),                \
               (&lds[32768]), 0, 0, VMW0, NOWAIT)

// ---------- GEMM1: qkv = x @ w_qkv, epilogue: rope + scatter + fused V^T ----
__global__ __launch_bounds__(512, 1) void gemm_qkv(
    const u16* __restrict__ A,    // xb [8192][2048]
    const u16* __restrict__ Bt,   // wqkvT [6144][2048]
    const float* __restrict__ cosT, const float* __restrict__ sinT,
    u16* __restrict__ qb, u16* __restrict__ kb,
    float* __restrict__ kout, float* __restrict__ vout,
    u16* __restrict__ vtout)
{
  extern __shared__ __align__(16) u16 lds[];   // 131072 B
  const int tid = threadIdx.x, wave = tid >> 6, lane = tid & 63;
  const int quad = lane >> 4, c16 = lane & 15;
  // bijective XCD swizzle: nwg = 24*32 = 768, 768 % 8 == 0, cpx = 96
  const int bid = blockIdx.y * 24 + blockIdx.x;
  const int swz = (bid & 7) * 96 + (bid >> 3);
  const int m0 = (swz / 24) * 256, n0 = (swz % 24) * 256;

  GEMM256_MAINLOOP(A, Bt)

  // ---- epilogue: rope + scatter, 4 passes of 64 rows through LDS ----
  // cbuf stride 258 (bank-stride 2 for V^T column reads = free 2-way;
  // acc-write quads spread to banks {0,8,16,24} = ~2-way; rope reads
  // consecutive). pass loop fully unrolled (rule #20).
  float* cbuf = (float*)lds;                  // [64][258] fp32 = 66.0 KB
  const int mat = n0 >> 11;                   // 0=q, 1=k, 2=v (block-uniform)
  const int hbase = (n0 & 2047) >> 7;
  // 1/sqrt(128) * log2(e) folded into q (attn uses exp2)
  const float qscale = 0.1275178689414753f;
#pragma unroll
  for (int pass = 0; pass < 4; ++pass) {
    __syncthreads();
    if ((wave >> 2) == (pass >> 1)) {
#pragma unroll
      for (int i = 0; i < 4; ++i) {
        const int mf = (pass & 1) * 4 + i;
#pragma unroll
        for (int j = 0; j < 4; ++j)
#pragma unroll
          for (int r = 0; r < 4; ++r)
            cbuf[(i * 16 + quad * 4 + r) * 258 + (wave & 3) * 64 + j * 16 + c16] = acc[mf][j][r];
      }
    }
    __syncthreads();
#pragma unroll
    for (int it = 0; it < 16; ++it) {
      int p = it * 512 + tid;          // 0..8191
      int lr = p >> 7;                 // local row 0..63
      int hc = (p >> 6) & 1;           // head-chunk within 256-wide tile
      int d = p & 63;
      float x1 = cbuf[lr * 258 + hc * 128 + d];
      float x2 = cbuf[lr * 258 + hc * 128 + 64 + d];
      int mg = m0 + pass * 64 + lr;
      int b = mg >> 11, t = mg & 2047;
      int h = hbase + hc;
      int idx = ((b * HDIM + h) * TDIM + t) * DDIM + d;
      if (mat == 2) {
        vout[idx] = x1; vout[idx + 64] = x2;
      } else {
        float cs = cosT[t * 64 + d], sn = sinT[t * 64 + d];
        float o1 = x1 * cs - x2 * sn;
        float o2 = x1 * sn + x2 * cs;
        if (mat == 0) {
          qb[idx] = f2b(o1 * qscale); qb[idx + 64] = f2b(o2 * qscale);
        } else {
          kout[idx] = o1; kout[idx + 64] = o2;
          kb[idx] = f2b(o1); kb[idx + 64] = f2b(o2);
        }
      }
    }
    // fused V^T: vt[bh][d][t] bf16, coalesced along t (replaces transpose_v)
    if (mat == 2) {
#pragma unroll
      for (int it = 0; it < 16; ++it) {
        int p = it * 512 + tid;        // 0..8191
        int tl = p & 63;               // t_local (lanes 0-63 share column)
        int c2 = p >> 6;               // 0..127  (d within head)
        float xA = cbuf[tl * 258 + c2];
        float xB = cbuf[tl * 258 + 128 + c2];
        int mg = m0 + pass * 64 + tl;
        int b = mg >> 11, t = mg & 2047;
        vtout[((b * HDIM + hbase) * DDIM + c2) * TDIM + t] = f2b(xA);
        vtout[((b * HDIM + hbase + 1) * DDIM + c2) * TDIM + t] = f2b(xB);
      }
    }
  }
}

// ---------- GEMM2: out = att @ w_proj ----------
__global__ __launch_bounds__(512, 1) void gemm_proj(
    const u16* __restrict__ A,    // att [8192][2048]
    const u16* __restrict__ Bt,   // wprojT [2048][2048]
    float* __restrict__ out)
{
  extern __shared__ __align__(16) u16 lds[];   // 131072 B
  const int tid = threadIdx.x, wave = tid >> 6, lane = tid & 63;
  const int quad = lane >> 4, c16 = lane & 15;
  // bijective XCD swizzle: nwg = 8*32 = 256, cpx = 32
  const int bid = blockIdx.y * 8 + blockIdx.x;
  const int swz = (bid & 7) * 32 + (bid >> 3);
  const int m0 = (swz >> 3) * 256, n0 = (swz & 7) * 256;

  GEMM256_MAINLOOP(A, Bt)

  const int wm = (wave >> 2) * 128, wn = (wave & 3) * 64;
#pragma unroll
  for (int mf = 0; mf < 8; ++mf)
#pragma unroll
    for (int nf = 0; nf < 4; ++nf)
#pragma unroll
      for (int r = 0; r < 4; ++r)
        out[(m0 + wm + mf * 16 + quad * 4 + r) * CDIM + n0 + wn + nf * 16 + c16] =
            acc[mf][nf][r];
}

// ---------- flash attention: 8-wave blocks, paired tiles, dbuf K/V ----------
// R14/R16 structure + wave-level skip of fully-masked chunks: wave w's
// rows end at q0+w*16+15; any chunk with kc0 > that is entirely masked
// (P==0 contributes nothing) -> skip QK/softmax/PV, keep staging+barriers
// (block-collective). Static-max softmax (log2, M=8); counted-vmcnt dbuf.
__global__ __launch_bounds__(512, 4) void attn(
    const u16* __restrict__ qb, const u16* __restrict__ kb,
    const u16* __restrict__ vt, u16* __restrict__ att)
{
  extern __shared__ __align__(16) u16 sh[];   // 81920 B dynamic
  u16* const psm = sh + 32768;        // per-wave 1024 u16 P buffer

  const int tid = threadIdx.x, wave = tid >> 6, lane = tid & 63;
  const int quad = lane >> 4, c16 = lane & 15;
  const int bx = blockIdx.x;          // 0..7 (pair slot)
  const int bh = blockIdx.y;          // 0..63

  // staging lane constants
  const int rlK = wave * 4 + (lane >> 4), chK = lane & 15;   // K/Q: 4-row strips
  const int rlV = wave * 8 + (lane >> 3), chV = lane & 7;    // V: 8-row strips

  for (int hv = 0; hv < 2; ++hv) {
    const int qt = hv ? (7 - bx) : (bx + 8);   // heavy tile first; 34 chunks total
    const int q0 = qt * 128;

    // ---- stage Q (128x128) into sh[0,16384) u16 (32 KB), extract frags ----
    {
      const u16* qg = qb + (bh * TDIM + q0) * DDIM;
#pragma unroll
      for (int r = 0; r < 4; ++r) {
        int row = r * 32 + rlK;
        gload_lds16(qg + row * DDIM + (chK ^ (row & 15)) * 8,
                    &sh[(r * 32 + wave * 4) * 128]);
      }
    }
    __syncthreads();
    bf16x8 qf[4];
#pragma unroll
    for (int kp = 0; kp < 4; ++kp)
      qf[kp] = *(const bf16x8*)&sh[(wave * 16 + c16) * 128 +
                                   (((kp * 4 + quad) ^ c16) * 8)];
    __syncthreads();   // all waves done reading Q area -> reusable for K/V

    f32x4 o[8];
    f32x4 zero = {0.f, 0.f, 0.f, 0.f};
#pragma unroll
    for (int jd = 0; jd < 8; ++jd) o[jd] = zero;
    float lrow[4];
#pragma unroll
    for (int r = 0; r < 4; ++r) lrow[r] = 0.f;

    const int nchunk = 2 * qt + 2;
    const int lastrow = q0 + wave * 16 + 15;   // this wave's last q-row

#define STAGE_KV(kcs, bufbase)                                                 \
    {                                                                          \
      const int kcs0 = (kcs) * 64;                                             \
      const u16* kg = kb + (bh * TDIM + kcs0) * DDIM;                          \
      _Pragma("unroll")                                                        \
      for (int r = 0; r < 2; ++r) {                                            \
        int row = r * 32 + rlK;                                                \
        gload_lds16(kg + row * DDIM + (chK ^ (row & 15)) * 8,                  \
                    &sh[(bufbase) + (r * 32 + wave * 4) * 128]);               \
      }                                                                        \
      const u16* vg = vt + bh * (DDIM * TDIM) + kcs0;                          \
      _Pragma("unroll")                                                        \
      for (int r = 0; r < 2; ++r) {                                            \
        int row = r * 64 + rlV;                                                \
        gload_lds16(vg + row * TDIM + (chV ^ (row & 7)) * 8,                   \
                    &sh[(bufbase) + 8192 + (r * 64 + wave * 8) * 64]);         \
      }                                                                        \
    }

    // prologue: stage chunk 0 into buf0 (4 loads/thread outstanding)
    STAGE_KV(0, 0)

    for (int kc = 0; kc < nchunk; ++kc) {
      const int kc0 = kc * 64;
      const int cur = kc & 1;
      const u16* ksm = sh + cur * 16384;
      const u16* vsm = ksm + 8192;

      // issue next chunk's staging into buf^1 (WAR-safe: its readers
      // finished before the end-barrier of iteration kc-1)
      if (kc + 1 < nchunk) {
        STAGE_KV(kc + 1, (cur ^ 1) * 16384)
        asm volatile("s_waitcnt vmcnt(4)" ::: "memory");  // completes kc's 4
      } else {
        asm volatile("s_waitcnt vmcnt(0)" ::: "memory");  // drain last
      }
      asm volatile("s_barrier" ::: "memory");             // publish chunk kc

      // wave-level skip: chunk entirely in this wave's masked future
      if (kc0 <= lastrow) {
        // S = Q K^T (log2-domain: scale*log2e pre-folded into Q)
        f32x4 st[4];
#pragma unroll
        for (int j = 0; j < 4; ++j) st[j] = zero;
#pragma unroll
        for (int kp = 0; kp < 4; ++kp) {
#pragma unroll
          for (int j = 0; j < 4; ++j) {
            bf16x8 bk = *(const bf16x8*)&ksm[(j * 16 + c16) * 128 +
                                             (((kp * 4 + quad) ^ c16) * 8)];
            st[j] = __builtin_amdgcn_mfma_f32_16x16x32_bf16(qf[kp], bk, st[j], 0, 0, 0);
          }
        }

        // static-max softmax: P = exp2(S - 8)
        u16* const pw = psm + wave * 1024;
        const bool dg = (kc0 + 63 > q0 + wave * 16);
        const int qrow_base = q0 + wave * 16 + quad * 4;
#pragma unroll
        for (int r = 0; r < 4; ++r) {
          const int row16 = quad * 4 + r;
          float sum = 0.f;
#pragma unroll
          for (int j = 0; j < 4; ++j) {
            float sv = st[j][r];
            if (dg && (kc0 + j * 16 + c16 > qrow_base + r)) sv = -INFINITY;
            float p = exp2f(sv - 8.0f);
            sum += p;
            int chunk = (j * 2 + (c16 >> 3)) ^ (row16 & 7);
            pw[row16 * 64 + chunk * 8 + (c16 & 7)] = f2b(p);
          }
          lrow[r] += sum;
        }

        asm volatile("s_waitcnt lgkmcnt(0)" ::: "memory");

        // O += P V
#pragma unroll
        for (int s = 0; s < 2; ++s) {
          const int chp = ((s * 4 + quad) ^ (c16 & 7)) * 8;
          bf16x8 ap = *(const bf16x8*)&pw[c16 * 64 + chp];
#pragma unroll
          for (int jd = 0; jd < 8; ++jd) {
            bf16x8 bv = *(const bf16x8*)&vsm[(jd * 16 + c16) * 64 + chp];
            o[jd] = __builtin_amdgcn_mfma_f32_16x16x32_bf16(ap, bv, o[jd], 0, 0, 0);
          }
        }
      }
      asm volatile("s_barrier" ::: "memory");  // WAR fence for next staging
    }
#undef STAGE_KV

    // epilogue: single cross-lane lrow reduce, normalize, write att
    const int b = bh >> 4, h = bh & 15;
    float ri[4];
#pragma unroll
    for (int r = 0; r < 4; ++r) {
      float s = lrow[r];
      s += __shfl_xor(s, 1, 64);
      s += __shfl_xor(s, 2, 64);
      s += __shfl_xor(s, 4, 64);
      s += __shfl_xor(s, 8, 64);
      ri[r] = 1.f / s;
    }
#pragma unroll
    for (int jd = 0; jd < 8; ++jd)
#pragma unroll
      for (int r = 0; r < 4; ++r) {
        int t = q0 + wave * 16 + quad * 4 + r;
        att[(b * TDIM + t) * CDIM + h * DDIM + jd * 16 + c16] = f2b(o[jd][r] * ri[r]);
      }
    __syncthreads();  // before hv=1 re-stages Q over buf0
  }
}

// ---------- launcher ----------
extern "C" void kernel_launch(void* const* d_in, const int* in_sizes, int n_in,
                              void* d_out, int out_size, void* d_ws, size_t ws_size,
                              hipStream_t stream) {
  (void)in_sizes; (void)n_in; (void)out_size; (void)ws_size;
  const float* x      = (const float*)d_in[0];
  const float* w_qkv  = (const float*)d_in[1];
  const float* w_proj = (const float*)d_in[2];
  float* out  = (float*)d_out;
  float* kout = out + 16777216;
  float* vout = out + 2 * 16777216;

  char* ws = (char*)d_ws;
  u16*   xb     = (u16*)(ws);                   // 33.5 MB (reused as att)
  u16*   wqkvT  = (u16*)(ws + 33554432);        // 25.2 MB
  u16*   wprojT = (u16*)(ws + 58720256);        // 8.4 MB
  float* cosT   = (float*)(ws + 67108864);      // 0.5 MB
  float* sinT   = (float*)(ws + 67633152);      // 0.5 MB
  u16*   qb     = (u16*)(ws + 68157440);        // 33.5 MB
  u16*   kb     = (u16*)(ws + 101711872);       // 33.5 MB
  u16*   vt     = (u16*)(ws + 135266304);       // 33.5 MB  (total ~169 MB)
  u16*   att    = xb;

  static int attr_set = 0;
  if (!attr_set) {
    hipFuncSetAttribute((const void*)gemm_qkv,
                        hipFuncAttributeMaxDynamicSharedMemorySize, 131072);
    hipFuncSetAttribute((const void*)gemm_proj,
                        hipFuncAttributeMaxDynamicSharedMemorySize, 131072);
    hipFuncSetAttribute((const void*)attn,
                        hipFuncAttributeMaxDynamicSharedMemorySize, 81920);
    attr_set = 1;
  }

  prep<<<33280, 256, 0, stream>>>(x, xb, w_qkv, wqkvT, w_proj, wprojT, cosT, sinT);
  gemm_qkv<<<dim3(24, 32), 512, 131072, stream>>>(xb, wqkvT, cosT, sinT, qb, kb, kout, vout, vt);
  attn<<<dim3(8, 64), 512, 81920, stream>>>(qb, kb, vt, att);
  gemm_proj<<<dim3(8, 32), 512, 131072, stream>>>(att, wprojT, out);
}

// Round 18
// 668.813 us; speedup vs baseline: 1.0369x; 1.0065x over previous
//
#include <hip/hip_runtime.h>
#include <math.h>

#define CDIM 2048
#define TDIM 2048
#define BDIM 4
#define HDIM 16
#define DDIM 128
#define M1   (BDIM * TDIM)   // 8192
#define N1   (3 * CDIM)      // 6144
#define KK   CDIM            // 2048
#define NT   32              // K tiles of 64

typedef unsigned short u16;
typedef __bf16 bf16x8 __attribute__((ext_vector_type(8)));
typedef float f32x4 __attribute__((ext_vector_type(4)));

// ---------- helpers ----------
__device__ __forceinline__ u16 f2b(float f) {
  union { float f; unsigned u; } x; x.f = f;
  unsigned r = x.u + 0x7fffu + ((x.u >> 16) & 1u);
  return (u16)(r >> 16);
}

__device__ __forceinline__ void gload_lds16(const void* g, void* l) {
  __builtin_amdgcn_global_load_lds(
      (__attribute__((address_space(1))) void*)g,
      (__attribute__((address_space(3))) void*)l, 16, 0, 0);
}

// ---------- fused prep kernel (R16, verified): convert_x + transpose_w x2 +
// rope_tab in ONE launch. Blocks: [0,16384) convert_x; [16384,28672) w_qkv;
// [28672,32768) w_proj; [32768,33280) rope_tab.
__global__ void prep(const float* __restrict__ x, u16* __restrict__ xb,
                     const float* __restrict__ w_qkv, u16* __restrict__ wqkvT,
                     const float* __restrict__ w_proj, u16* __restrict__ wprojT,
                     float* __restrict__ cosT, float* __restrict__ sinT) {
  __shared__ float tile[32][33];
  const int gb = blockIdx.x;
  if (gb < 16384) {
    int i = gb * 256 + threadIdx.x;
    float4 v = ((const float4*)x)[i];
    unsigned long long o = (unsigned long long)f2b(v.x)
                         | ((unsigned long long)f2b(v.y) << 16)
                         | ((unsigned long long)f2b(v.z) << 32)
                         | ((unsigned long long)f2b(v.w) << 48);
    ((unsigned long long*)xb)[i] = o;
  } else if (gb < 32768) {
    const float* w; u16* wt; int N, r;
    if (gb < 28672) { w = w_qkv;  wt = wqkvT;  N = N1;   r = gb - 16384; }
    else            { w = w_proj; wt = wprojT; N = CDIM; r = gb - 28672; }
    const int nblk = N >> 5;
    const int n0 = (r % nblk) * 32, k0 = (r / nblk) * 32;
    const int tx = threadIdx.x & 31, ty = threadIdx.x >> 5;
    for (int rr = ty; rr < 32; rr += 8)
      tile[rr][tx] = w[(k0 + rr) * N + n0 + tx];
    __syncthreads();
    for (int rr = ty; rr < 32; rr += 8)
      wt[(n0 + rr) * KK + k0 + tx] = f2b(tile[tx][rr]);
  } else {
    int i = (gb - 32768) * 256 + threadIdx.x;   // 0 .. 2048*64-1
    int t = i >> 6, d = i & 63;
    float inv = exp2f(-(float)d * (13.287712379549449f / 64.0f));
    float a = (float)t * inv;
    cosT[i] = cosf(a);
    sinT[i] = sinf(a);
  }
}

// =====================================================================
// 256x256-tile, BK=64, 8-wave (2Mx4N) GEMM — R5 schedule (best measured).
// =====================================================================

#define VMW4 asm volatile("s_waitcnt vmcnt(4)" ::: "memory");
#define VMW2 asm volatile("s_waitcnt vmcnt(2)" ::: "memory");
#define VMW0 asm volatile("s_waitcnt vmcnt(0)" ::: "memory");
#define NOWAIT

#define GEMM256_TILE(bufA_, bufB_, nA_, nB_, kno_, STG, WMID, WEND)            \
  {                                                                            \
    __builtin_amdgcn_s_barrier();  /* publishes A-lo,B-lo,B-hi(t); WAR */      \
    bf16x8 aX[4][2], aY[4][2], bX[2][2], bY[2][2];                             \
    /* q0 frags: A-lo, B-lo */                                                 \
    _Pragma("unroll")                                                          \
    for (int i = 0; i < 4; ++i)                                                \
      _Pragma("unroll")                                                        \
      for (int kh = 0; kh < 2; ++kh)                                           \
        aX[i][kh] = *(const bf16x8*)&(bufA_)[aoff + i * 1024 +                 \
                                             (((kh * 4 + quad) ^ rsw) * 8)];   \
    _Pragma("unroll")                                                          \
    for (int j = 0; j < 2; ++j)                                                \
      _Pragma("unroll")                                                        \
      for (int kh = 0; kh < 2; ++kh)                                           \
        bX[j][kh] = *(const bf16x8*)&(bufB_)[boff + j * 1024 +                 \
                                             (((kh * 4 + quad) ^ rsw) * 8)];   \
    /* q0: m-lo x n-lo */                                                      \
    __builtin_amdgcn_s_setprio(1);                                             \
    _Pragma("unroll")                                                          \
    for (int i = 0; i < 4; ++i)                                                \
      _Pragma("unroll")                                                        \
      for (int j = 0; j < 2; ++j)                                              \
        _Pragma("unroll")                                                      \
        for (int kh = 0; kh < 2; ++kh)                                         \
          acc[i][j] = __builtin_amdgcn_mfma_f32_16x16x32_bf16(                 \
              aX[i][kh], bX[j][kh], acc[i][j], 0, 0, 0);                       \
    __builtin_amdgcn_s_setprio(0);                                             \
    /* pre-read q1 frags: B-hi */                                              \
    _Pragma("unroll")                                                          \
    for (int j = 0; j < 2; ++j)                                                \
      _Pragma("unroll")                                                        \
      for (int kh = 0; kh < 2; ++kh)                                           \
        bY[j][kh] = *(const bf16x8*)&(bufB_)[8192 + boff + j * 1024 +          \
                                             (((kh * 4 + quad) ^ rsw) * 8)];   \
    if (STG) {                                                                 \
      _Pragma("unroll")                                                        \
      for (int q = 0; q < 2; ++q)                                              \
        gload_lds16(AgBase + (q * 128) * KK + (kno_), &(nA_)[q * 4096 + ldsw]);\
      _Pragma("unroll")                                                        \
      for (int q = 0; q < 2; ++q)                                              \
        gload_lds16(BgBase + (q * 128) * KK + (kno_),                          \
                    &(nB_)[q * 4096 + ldsw]);                                  \
    }                                                                          \
    WMID                                                                       \
    __builtin_amdgcn_s_barrier();  /* publishes A-hi(t) */                     \
    /* q1: m-lo x n-hi */                                                      \
    __builtin_amdgcn_s_setprio(1);                                             \
    _Pragma("unroll")                                                          \
    for (int i = 0; i < 4; ++i)                                                \
      _Pragma("unroll")                                                        \
      for (int j = 0; j < 2; ++j)                                              \
        _Pragma("unroll")                                                      \
        for (int kh = 0; kh < 2; ++kh)                                         \
          acc[i][2 + j] = __builtin_amdgcn_mfma_f32_16x16x32_bf16(             \
              aX[i][kh], bY[j][kh], acc[i][2 + j], 0, 0, 0);                   \
    __builtin_amdgcn_s_setprio(0);                                             \
    /* pre-read q2 frags: A-hi */                                              \
    _Pragma("unroll")                                                          \
    for (int i = 0; i < 4; ++i)                                                \
      _Pragma("unroll")                                                        \
      for (int kh = 0; kh < 2; ++kh)                                           \
        aY[i][kh] = *(const bf16x8*)&(bufA_)[8192 + aoff + i * 1024 +          \
                                             (((kh * 4 + quad) ^ rsw) * 8)];   \
    if (STG) {                                                                 \
      _Pragma("unroll")                                                        \
      for (int q = 0; q < 2; ++q)                                              \
        gload_lds16(BgBase + (q * 128 + 32) * KK + (kno_),                     \
                    &(nB_)[8192 + q * 4096 + ldsw]);                           \
    }                                                                          \
    /* q2: m-hi x n-hi */                                                      \
    __builtin_amdgcn_s_setprio(1);                                             \
    _Pragma("unroll")                                                          \
    for (int i = 0; i < 4; ++i)                                                \
      _Pragma("unroll")                                                        \
      for (int j = 0; j < 2; ++j)                                              \
        _Pragma("unroll")                                                      \
        for (int kh = 0; kh < 2; ++kh)                                         \
          acc[4 + i][2 + j] = __builtin_amdgcn_mfma_f32_16x16x32_bf16(         \
              aY[i][kh], bY[j][kh], acc[4 + i][2 + j], 0, 0, 0);               \
    __builtin_amdgcn_s_setprio(0);                                             \
    if (STG) {                                                                 \
      _Pragma("unroll")                                                        \
      for (int q = 0; q < 2; ++q)                                              \
        gload_lds16(AgBase + (q * 128 + 64) * KK + (kno_),                     \
                    &(nA_)[8192 + q * 4096 + ldsw]);                           \
    }                                                                          \
    /* q3: m-hi x n-lo */                                                      \
    __builtin_amdgcn_s_setprio(1);                                             \
    _Pragma("unroll")                                                          \
    for (int i = 0; i < 4; ++i)                                                \
      _Pragma("unroll")                                                        \
      for (int j = 0; j < 2; ++j)                                              \
        _Pragma("unroll")                                                      \
        for (int kh = 0; kh < 2; ++kh)                                         \
          acc[4 + i][j] = __builtin_amdgcn_mfma_f32_16x16x32_bf16(             \
              aY[i][kh], bX[j][kh], acc[4 + i][j], 0, 0, 0);                   \
    __builtin_amdgcn_s_setprio(0);                                             \
    WEND                                                                       \
  }

#define GEMM256_MAINLOOP(APTR, BPTR)                                           \
  const int rA = lane >> 3, cA = lane & 7;                                     \
  const int w8r = wave * 8 + rA;                                               \
  const int swz8 = (cA ^ rA) * 8;                                              \
  const u16* AgBase = (APTR) + (m0 + w8r) * KK + swz8;                         \
  const int nb = ((w8r >> 5) * 64) + (w8r & 31);                               \
  const u16* BgBase = (BPTR) + (n0 + nb) * KK + swz8;                          \
  const int ldsw = wave * 512;                                                 \
  const int rsw = c16 & 7;                                                     \
  const int aoff = (((wave >> 2) * 64) + c16) * 64;                            \
  const int boff = (((wave & 3) * 32) + c16) * 64;                             \
  f32x4 acc[8][4];                                                             \
  {                                                                            \
    f32x4 z = {0.f, 0.f, 0.f, 0.f};                                            \
    _Pragma("unroll")                                                          \
    for (int i = 0; i < 8; ++i)                                                \
      _Pragma("unroll")                                                        \
      for (int j = 0; j < 4; ++j) acc[i][j] = z;                               \
  }                                                                            \
  _Pragma("unroll")                                                            \
  for (int q = 0; q < 2; ++q)                                                  \
    gload_lds16(AgBase + (q * 128) * KK, &lds[q * 4096 + ldsw]);               \
  _Pragma("unroll")                                                            \
  for (int q = 0; q < 2; ++q)                                                  \
    gload_lds16(BgBase + (q * 128) * KK, &lds[32768 + q * 4096 + ldsw]);       \
  _Pragma("unroll")                                                            \
  for (int q = 0; q < 2; ++q)                                                  \
    gload_lds16(BgBase + (q * 128 + 32) * KK,                                  \
                &lds[32768 + 8192 + q * 4096 + ldsw]);                         \
  _Pragma("unroll")                                                            \
  for (int q = 0; q < 2; ++q)                                                  \
    gload_lds16(AgBase + (q * 128 + 64) * KK, &lds[8192 + q * 4096 + ldsw]);   \
  VMW2                                                                         \
  for (int kt = 0; kt < NT - 1; ++kt) {                                        \
    const int cur = kt & 1;                                                    \
    const u16* bA = &lds[cur * 16384];                                         \
    const u16* bB = &lds[32768 + cur * 16384];                                 \
    u16* nA = &lds[(cur ^ 1) * 16384];                                         \
    u16* nB = &lds[32768 + (cur ^ 1) * 16384];                                 \
    const int kno = (kt + 1) * 64;                                             \
    GEMM256_TILE(bA, bB, nA, nB, kno, 1, VMW4, VMW2)                           \
  }                                                                            \
  GEMM256_TILE((&lds[16384]), (&lds[32768 + 16384]), (&lds[0]),                \
               (&lds[32768]), 0, 0, VMW0, NOWAIT)

// ---------- GEMM1: qkv = x @ w_qkv, epilogue: rope + scatter + fused V^T ----
__global__ __launch_bounds__(512, 1) void gemm_qkv(
    const u16* __restrict__ A,    // xb [8192][2048]
    const u16* __restrict__ Bt,   // wqkvT [6144][2048]
    const float* __restrict__ cosT, const float* __restrict__ sinT,
    u16* __restrict__ qb, u16* __restrict__ kb,
    float* __restrict__ kout, float* __restrict__ vout,
    u16* __restrict__ vtout)
{
  extern __shared__ __align__(16) u16 lds[];   // 131072 B
  const int tid = threadIdx.x, wave = tid >> 6, lane = tid & 63;
  const int quad = lane >> 4, c16 = lane & 15;
  // bijective XCD swizzle: nwg = 24*32 = 768, 768 % 8 == 0, cpx = 96
  const int bid = blockIdx.y * 24 + blockIdx.x;
  const int swz = (bid & 7) * 96 + (bid >> 3);
  const int m0 = (swz / 24) * 256, n0 = (swz % 24) * 256;

  GEMM256_MAINLOOP(A, Bt)

  // ---- epilogue: rope + scatter, 4 passes of 64 rows through LDS ----
  // cbuf stride 261 (measured-best: 1.57M conflicts vs 2.1M at 258).
  // pass loop fully unrolled (rule #20).
  float* cbuf = (float*)lds;                  // [64][261] fp32 = 66.8 KB
  const int mat = n0 >> 11;                   // 0=q, 1=k, 2=v (block-uniform)
  const int hbase = (n0 & 2047) >> 7;
  // 1/sqrt(128) * log2(e) folded into q (attn uses exp2)
  const float qscale = 0.1275178689414753f;
#pragma unroll
  for (int pass = 0; pass < 4; ++pass) {
    __syncthreads();
    if ((wave >> 2) == (pass >> 1)) {
#pragma unroll
      for (int i = 0; i < 4; ++i) {
        const int mf = (pass & 1) * 4 + i;
#pragma unroll
        for (int j = 0; j < 4; ++j)
#pragma unroll
          for (int r = 0; r < 4; ++r)
            cbuf[(i * 16 + quad * 4 + r) * 261 + (wave & 3) * 64 + j * 16 + c16] = acc[mf][j][r];
      }
    }
    __syncthreads();
#pragma unroll
    for (int it = 0; it < 16; ++it) {
      int p = it * 512 + tid;          // 0..8191
      int lr = p >> 7;                 // local row 0..63
      int hc = (p >> 6) & 1;           // head-chunk within 256-wide tile
      int d = p & 63;
      float x1 = cbuf[lr * 261 + hc * 128 + d];
      float x2 = cbuf[lr * 261 + hc * 128 + 64 + d];
      int mg = m0 + pass * 64 + lr;
      int b = mg >> 11, t = mg & 2047;
      int h = hbase + hc;
      int idx = ((b * HDIM + h) * TDIM + t) * DDIM + d;
      if (mat == 2) {
        vout[idx] = x1; vout[idx + 64] = x2;
      } else {
        float cs = cosT[t * 64 + d], sn = sinT[t * 64 + d];
        float o1 = x1 * cs - x2 * sn;
        float o2 = x1 * sn + x2 * cs;
        if (mat == 0) {
          qb[idx] = f2b(o1 * qscale); qb[idx + 64] = f2b(o2 * qscale);
        } else {
          kout[idx] = o1; kout[idx + 64] = o2;
          kb[idx] = f2b(o1); kb[idx + 64] = f2b(o2);
        }
      }
    }
    // fused V^T: vt[bh][d][t] bf16, coalesced along t (replaces transpose_v)
    if (mat == 2) {
#pragma unroll
      for (int it = 0; it < 16; ++it) {
        int p = it * 512 + tid;        // 0..8191
        int tl = p & 63;               // t_local (lanes 0-63 share column)
        int c2 = p >> 6;               // 0..127  (d within head)
        float xA = cbuf[tl * 261 + c2];
        float xB = cbuf[tl * 261 + 128 + c2];
        int mg = m0 + pass * 64 + tl;
        int b = mg >> 11, t = mg & 2047;
        vtout[((b * HDIM + hbase) * DDIM + c2) * TDIM + t] = f2b(xA);
        vtout[((b * HDIM + hbase + 1) * DDIM + c2) * TDIM + t] = f2b(xB);
      }
    }
  }
}

// ---------- GEMM2: out = att @ w_proj ----------
__global__ __launch_bounds__(512, 1) void gemm_proj(
    const u16* __restrict__ A,    // att [8192][2048]
    const u16* __restrict__ Bt,   // wprojT [2048][2048]
    float* __restrict__ out)
{
  extern __shared__ __align__(16) u16 lds[];   // 131072 B
  const int tid = threadIdx.x, wave = tid >> 6, lane = tid & 63;
  const int quad = lane >> 4, c16 = lane & 15;
  // bijective XCD swizzle: nwg = 8*32 = 256, cpx = 32
  const int bid = blockIdx.y * 8 + blockIdx.x;
  const int swz = (bid & 7) * 32 + (bid >> 3);
  const int m0 = (swz >> 3) * 256, n0 = (swz & 7) * 256;

  GEMM256_MAINLOOP(A, Bt)

  const int wm = (wave >> 2) * 128, wn = (wave & 3) * 64;
#pragma unroll
  for (int mf = 0; mf < 8; ++mf)
#pragma unroll
    for (int nf = 0; nf < 4; ++nf)
#pragma unroll
      for (int r = 0; r < 4; ++r)
        out[(m0 + wm + mf * 16 + quad * 4 + r) * CDIM + n0 + wn + nf * 16 + c16] =
            acc[mf][nf][r];
}

// ---------- flash attention: 8-wave blocks, paired tiles, dbuf K/V ----------
// R17 structure (best measured): wave-level skip of fully-masked chunks;
// static-max softmax (log2, M=8); counted-vmcnt dbuf K/V prefetch.
__global__ __launch_bounds__(512, 4) void attn(
    const u16* __restrict__ qb, const u16* __restrict__ kb,
    const u16* __restrict__ vt, u16* __restrict__ att)
{
  extern __shared__ __align__(16) u16 sh[];   // 81920 B dynamic
  u16* const psm = sh + 32768;        // per-wave 1024 u16 P buffer

  const int tid = threadIdx.x, wave = tid >> 6, lane = tid & 63;
  const int quad = lane >> 4, c16 = lane & 15;
  const int bx = blockIdx.x;          // 0..7 (pair slot)
  const int bh = blockIdx.y;          // 0..63

  // staging lane constants
  const int rlK = wave * 4 + (lane >> 4), chK = lane & 15;   // K/Q: 4-row strips
  const int rlV = wave * 8 + (lane >> 3), chV = lane & 7;    // V: 8-row strips

  for (int hv = 0; hv < 2; ++hv) {
    const int qt = hv ? (7 - bx) : (bx + 8);   // heavy tile first; 34 chunks total
    const int q0 = qt * 128;

    // ---- stage Q (128x128) into sh[0,16384) u16 (32 KB), extract frags ----
    {
      const u16* qg = qb + (bh * TDIM + q0) * DDIM;
#pragma unroll
      for (int r = 0; r < 4; ++r) {
        int row = r * 32 + rlK;
        gload_lds16(qg + row * DDIM + (chK ^ (row & 15)) * 8,
                    &sh[(r * 32 + wave * 4) * 128]);
      }
    }
    __syncthreads();
    bf16x8 qf[4];
#pragma unroll
    for (int kp = 0; kp < 4; ++kp)
      qf[kp] = *(const bf16x8*)&sh[(wave * 16 + c16) * 128 +
                                   (((kp * 4 + quad) ^ c16) * 8)];
    __syncthreads();   // all waves done reading Q area -> reusable for K/V

    f32x4 o[8];
    f32x4 zero = {0.f, 0.f, 0.f, 0.f};
#pragma unroll
    for (int jd = 0; jd < 8; ++jd) o[jd] = zero;
    float lrow[4];
#pragma unroll
    for (int r = 0; r < 4; ++r) lrow[r] = 0.f;

    const int nchunk = 2 * qt + 2;
    const int lastrow = q0 + wave * 16 + 15;   // this wave's last q-row

#define STAGE_KV(kcs, bufbase)                                                 \
    {                                                                          \
      const int kcs0 = (kcs) * 64;                                             \
      const u16* kg = kb + (bh * TDIM + kcs0) * DDIM;                          \
      _Pragma("unroll")                                                        \
      for (int r = 0; r < 2; ++r) {                                            \
        int row = r * 32 + rlK;                                                \
        gload_lds16(kg + row * DDIM + (chK ^ (row & 15)) * 8,                  \
                    &sh[(bufbase) + (r * 32 + wave * 4) * 128]);               \
      }                                                                        \
      const u16* vg = vt + bh * (DDIM * TDIM) + kcs0;                          \
      _Pragma("unroll")                                                        \
      for (int r = 0; r < 2; ++r) {                                            \
        int row = r * 64 + rlV;                                                \
        gload_lds16(vg + row * TDIM + (chV ^ (row & 7)) * 8,                   \
                    &sh[(bufbase) + 8192 + (r * 64 + wave * 8) * 64]);         \
      }                                                                        \
    }

    // prologue: stage chunk 0 into buf0 (4 loads/thread outstanding)
    STAGE_KV(0, 0)

    for (int kc = 0; kc < nchunk; ++kc) {
      const int kc0 = kc * 64;
      const int cur = kc & 1;
      const u16* ksm = sh + cur * 16384;
      const u16* vsm = ksm + 8192;

      // issue next chunk's staging into buf^1 (WAR-safe: its readers
      // finished before the end-barrier of iteration kc-1)
      if (kc + 1 < nchunk) {
        STAGE_KV(kc + 1, (cur ^ 1) * 16384)
        asm volatile("s_waitcnt vmcnt(4)" ::: "memory");  // completes kc's 4
      } else {
        asm volatile("s_waitcnt vmcnt(0)" ::: "memory");  // drain last
      }
      asm volatile("s_barrier" ::: "memory");             // publish chunk kc

      // wave-level skip: chunk entirely in this wave's masked future
      if (kc0 <= lastrow) {
        // S = Q K^T (log2-domain: scale*log2e pre-folded into Q)
        f32x4 st[4];
#pragma unroll
        for (int j = 0; j < 4; ++j) st[j] = zero;
#pragma unroll
        for (int kp = 0; kp < 4; ++kp) {
#pragma unroll
          for (int j = 0; j < 4; ++j) {
            bf16x8 bk = *(const bf16x8*)&ksm[(j * 16 + c16) * 128 +
                                             (((kp * 4 + quad) ^ c16) * 8)];
            st[j] = __builtin_amdgcn_mfma_f32_16x16x32_bf16(qf[kp], bk, st[j], 0, 0, 0);
          }
        }

        // static-max softmax: P = exp2(S - 8)
        u16* const pw = psm + wave * 1024;
        const bool dg = (kc0 + 63 > q0 + wave * 16);
        const int qrow_base = q0 + wave * 16 + quad * 4;
#pragma unroll
        for (int r = 0; r < 4; ++r) {
          const int row16 = quad * 4 + r;
          float sum = 0.f;
#pragma unroll
          for (int j = 0; j < 4; ++j) {
            float sv = st[j][r];
            if (dg && (kc0 + j * 16 + c16 > qrow_base + r)) sv = -INFINITY;
            float p = exp2f(sv - 8.0f);
            sum += p;
            int chunk = (j * 2 + (c16 >> 3)) ^ (row16 & 7);
            pw[row16 * 64 + chunk * 8 + (c16 & 7)] = f2b(p);
          }
          lrow[r] += sum;
        }

        asm volatile("s_waitcnt lgkmcnt(0)" ::: "memory");

        // O += P V
#pragma unroll
        for (int s = 0; s < 2; ++s) {
          const int chp = ((s * 4 + quad) ^ (c16 & 7)) * 8;
          bf16x8 ap = *(const bf16x8*)&pw[c16 * 64 + chp];
#pragma unroll
          for (int jd = 0; jd < 8; ++jd) {
            bf16x8 bv = *(const bf16x8*)&vsm[(jd * 16 + c16) * 64 + chp];
            o[jd] = __builtin_amdgcn_mfma_f32_16x16x32_bf16(ap, bv, o[jd], 0, 0, 0);
          }
        }
      }
      asm volatile("s_barrier" ::: "memory");  // WAR fence for next staging
    }
#undef STAGE_KV

    // epilogue: single cross-lane lrow reduce, normalize, write att
    const int b = bh >> 4, h = bh & 15;
    float ri[4];
#pragma unroll
    for (int r = 0; r < 4; ++r) {
      float s = lrow[r];
      s += __shfl_xor(s, 1, 64);
      s += __shfl_xor(s, 2, 64);
      s += __shfl_xor(s, 4, 64);
      s += __shfl_xor(s, 8, 64);
      ri[r] = 1.f / s;
    }
#pragma unroll
    for (int jd = 0; jd < 8; ++jd)
#pragma unroll
      for (int r = 0; r < 4; ++r) {
        int t = q0 + wave * 16 + quad * 4 + r;
        att[(b * TDIM + t) * CDIM + h * DDIM + jd * 16 + c16] = f2b(o[jd][r] * ri[r]);
      }
    __syncthreads();  // before hv=1 re-stages Q over buf0
  }
}

// ---------- launcher ----------
extern "C" void kernel_launch(void* const* d_in, const int* in_sizes, int n_in,
                              void* d_out, int out_size, void* d_ws, size_t ws_size,
                              hipStream_t stream) {
  (void)in_sizes; (void)n_in; (void)out_size; (void)ws_size;
  const float* x      = (const float*)d_in[0];
  const float* w_qkv  = (const float*)d_in[1];
  const float* w_proj = (const float*)d_in[2];
  float* out  = (float*)d_out;
  float* kout = out + 16777216;
  float* vout = out + 2 * 16777216;

  char* ws = (char*)d_ws;
  u16*   xb     = (u16*)(ws);                   // 33.5 MB (reused as att)
  u16*   wqkvT  = (u16*)(ws + 33554432);        // 25.2 MB
  u16*   wprojT = (u16*)(ws + 58720256);        // 8.4 MB
  float* cosT   = (float*)(ws + 67108864);      // 0.5 MB
  float* sinT   = (float*)(ws + 67633152);      // 0.5 MB
  u16*   qb     = (u16*)(ws + 68157440);        // 33.5 MB
  u16*   kb     = (u16*)(ws + 101711872);       // 33.5 MB
  u16*   vt     = (u16*)(ws + 135266304);       // 33.5 MB  (total ~169 MB)
  u16*   att    = xb;

  static int attr_set = 0;
  if (!attr_set) {
    hipFuncSetAttribute((const void*)gemm_qkv,
                        hipFuncAttributeMaxDynamicSharedMemorySize, 131072);
    hipFuncSetAttribute((const void*)gemm_proj,
                        hipFuncAttributeMaxDynamicSharedMemorySize, 131072);
    hipFuncSetAttribute((const void*)attn,
                        hipFuncAttributeMaxDynamicSharedMemorySize, 81920);
    attr_set = 1;
  }

  prep<<<33280, 256, 0, stream>>>(x, xb, w_qkv, wqkvT, w_proj, wprojT, cosT, sinT);
  gemm_qkv<<<dim3(24, 32), 512, 131072, stream>>>(xb, wqkvT, cosT, sinT, qb, kb, kout, vout, vt);
  attn<<<dim3(8, 64), 512, 81920, stream>>>(qb, kb, vt, att);
  gemm_proj<<<dim3(8, 32), 512, 131072, stream>>>(att, wprojT, out);
}